// Round 8
// baseline (695.737 us; speedup 1.0000x reference)
//
#include <hip/hip_runtime.h>

#define NN 100000
#define NNP 100032   // padded to 1563*64 rows; rows NN..NNP-1 are written as zeros
#define NE 1600000
#define NP 200000
#define NBKT 782     // buckets of 128 nodes
#define BCAP 3072    // per-bucket arena capacity (mean 2046)
#define BKB 4096     // edges per k_bucket block

typedef short s16x8 __attribute__((ext_vector_type(8)));
typedef float f32x4 __attribute__((ext_vector_type(4)));

__device__ __forceinline__ unsigned short f2bf(float f) {  // RNE fp32->bf16
  unsigned int u = __float_as_uint(f);
  u += 0x7fffu + ((u >> 16) & 1u);
  return (unsigned short)(u >> 16);
}

__device__ __forceinline__ void upadd(uint u, float& lo, float& hi) {
  lo += __uint_as_float(u << 16);
  hi += __uint_as_float(u & 0xffff0000u);
}

// ---------------- setup: gcur init + W pre-pack, one launch ----------------
template <int NT>
__device__ __forceinline__ void prepw_dev(const float* __restrict__ W,
                                          uint* __restrict__ Wt, int tid) {
  constexpr int COUT = NT * 16;
  if (tid >= 4 * NT * 64) return;
  int lane = tid & 63, comb = tid >> 6;
  int ks = comb / NT, tl = comb % NT;
  int q = lane >> 4, n = lane & 15;
  uint w[4];
#pragma unroll
  for (int jj = 0; jj < 4; ++jj) {
    int k0 = ks * 32 + q * 8 + 2 * jj;
    uint lo = f2bf(W[k0 * COUT + tl * 16 + n]);
    uint hi = f2bf(W[(k0 + 1) * COUT + tl * 16 + n]);
    w[jj] = lo | (hi << 16);
  }
  ((uint4*)Wt)[comb * 64 + lane] = make_uint4(w[0], w[1], w[2], w[3]);
}

__global__ __launch_bounds__(256) void k_setup(const float* __restrict__ W1,
                                               const float* __restrict__ W2,
                                               const float* __restrict__ W3,
                                               uint* __restrict__ Wt1,
                                               uint* __restrict__ Wt2,
                                               uint* __restrict__ Wt3,
                                               int* __restrict__ gcur) {
  int b = blockIdx.x, t = threadIdx.x;
  if (b < 4) {
    int i = b * 256 + t;
    if (i < 1024) gcur[i] = i * BCAP;
  } else if (b < 12) {
    prepw_dev<8>(W1, Wt1, (b - 4) * 256 + t);
  } else if (b < 20) {
    prepw_dev<8>(W2, Wt2, (b - 12) * 256 + t);
  } else {
    prepw_dev<4>(W3, Wt3, (b - 20) * 256 + t);
  }
}

// ---------------- bucket-sort phase A ----------------
__global__ __launch_bounds__(256) void k_bucket(const int* __restrict__ ei,
                                                int* __restrict__ gcur,
                                                int* __restrict__ aux) {
  __shared__ int cnt[1024];
  __shared__ int scn[1024];
  __shared__ int cur[1024];
  __shared__ int sc[256];
  __shared__ int sorted[BKB];
  __shared__ unsigned short sbkt[BKB];
  const int t = threadIdx.x;
  const int base = blockIdx.x * BKB;

  for (int i = t; i < 1024; i += 256) cnt[i] = 0;
  __syncthreads();

  int pk[16], bk[16];
#pragma unroll
  for (int i = 0; i < 16; ++i) {
    int e = base + t + 256 * i;
    if (e < NE) {
      int src = ei[e], dst = ei[NE + e];
      bk[i] = dst >> 7;
      pk[i] = src | ((dst & 127) << 17);
      atomicAdd(&cnt[bk[i]], 1);
    } else {
      bk[i] = -1;
    }
  }
  __syncthreads();

  int s0 = cnt[4 * t], s1 = cnt[4 * t + 1], s2 = cnt[4 * t + 2], s3 = cnt[4 * t + 3];
  int local = s0 + s1 + s2 + s3;
  sc[t] = local;
  __syncthreads();
  for (int off = 1; off < 256; off <<= 1) {
    int a = (t >= off) ? sc[t - off] : 0;
    __syncthreads();
    sc[t] += a;
    __syncthreads();
  }
  int b0 = sc[t] - local;
  scn[4 * t] = b0;
  scn[4 * t + 1] = b0 + s0;
  scn[4 * t + 2] = b0 + s0 + s1;
  scn[4 * t + 3] = b0 + s0 + s1 + s2;
  cur[4 * t] = scn[4 * t];
  cur[4 * t + 1] = scn[4 * t + 1];
  cur[4 * t + 2] = scn[4 * t + 2];
  cur[4 * t + 3] = scn[4 * t + 3];
  __syncthreads();
  const int tot = sc[255];

#pragma unroll
  for (int i = 0; i < 16; ++i) {
    if (bk[i] >= 0) {
      int pos = atomicAdd(&cur[bk[i]], 1);
      sorted[pos] = pk[i];
      sbkt[pos] = (unsigned short)bk[i];
    }
  }
  __syncthreads();

  for (int b = t; b < 1024; b += 256) {
    int c = cnt[b];
    if (c > 0) cur[b] = atomicAdd(&gcur[b], c);
  }
  __syncthreads();

  for (int k = t; k < tot; k += 256) {
    int b = sbkt[k];
    aux[cur[b] + (k - scn[b])] = sorted[k];
  }
}

// ---------------- merged CSR finalize ----------------
__global__ __launch_bounds__(256) void k_csr(const int* __restrict__ gcur,
                                             const int* __restrict__ aux,
                                             int* __restrict__ row_ptr,
                                             float* __restrict__ dinv,
                                             int* __restrict__ col) {
  __shared__ int red[256];
  __shared__ int c[128];
  __shared__ int cur[128];
  const int b = blockIdx.x, t = threadIdx.x;
  int p = 0;
  for (int i = t; i < b; i += 256) p += gcur[i] - i * BCAP;
  red[t] = p;
  if (t < 128) c[t] = 0;
  __syncthreads();
  for (int off = 128; off > 0; off >>= 1) {
    if (t < off) red[t] += red[t + off];
    __syncthreads();
  }
  const int base = red[0];
  const int m = gcur[b] - b * BCAP;
  const int* a = aux + (size_t)b * BCAP;
  __syncthreads();
  for (int k = t; k < m; k += 256) atomicAdd(&c[a[k] >> 17], 1);
  __syncthreads();
  int val = (t < 128) ? c[t] : 0;
  red[t] = val;
  __syncthreads();
  for (int off = 1; off < 128; off <<= 1) {
    int add = (t >= off && t < 128) ? red[t - off] : 0;
    __syncthreads();
    if (t < 128) red[t] += add;
    __syncthreads();
  }
  if (t < 128) {
    int excl = red[t] - val + base;
    int node = b * 128 + t;
    if (node < NN) {
      row_ptr[node] = excl;
      dinv[node] = rsqrtf((float)(val + 1));
      cur[t] = excl;
    }
  }
  if (b == NBKT - 1 && t == 0) row_ptr[NN] = base + m;
  __syncthreads();
  for (int k = t; k < m; k += 256) {
    int pk2 = a[k];
    int pos = atomicAdd(&cur[pk2 >> 17], 1);
    col[pos] = pk2 & 0x1FFFF;
  }
}

// ---------------- MFMA GEMM (padding rows written as zeros) ----------------
template <int COUT, bool AFP32>
__global__ __launch_bounds__(256) void k_gemm_mfma(const void* __restrict__ Av,
                                                   const uint* __restrict__ Wt,
                                                   const float* __restrict__ dinv,
                                                   unsigned short* __restrict__ T) {
  constexpr int NT = COUT / 16;
  __shared__ __align__(16) uint Wlds[4 * NT * 64 * 4];
  __shared__ __align__(16) unsigned short Obuf[64 * COUT];
  const int t = threadIdx.x;
  {
    const uint4* src = (const uint4*)Wt;
    uint4* dst = (uint4*)Wlds;
    for (int i = t; i < 4 * NT * 64; i += 256) dst[i] = src[i];
  }
  __syncthreads();

  const int wv = t >> 6, lane = t & 63;
  const int n = lane & 15, quad = lane >> 4;
  const int rbase = blockIdx.x * 64 + wv * 16;

  union AB { uint4 u; s16x8 s; };
  AB a[4];
  if constexpr (AFP32) {
    const float* A = (const float*)Av;
    int row = rbase + n;
    if (row >= NN) row = NN - 1;  // input x is exactly NN rows
    const float* ap = A + (size_t)row * 128;
#pragma unroll
    for (int ks = 0; ks < 4; ++ks) {
      float4 v0 = *(const float4*)(ap + ks * 32 + quad * 8);
      float4 v1 = *(const float4*)(ap + ks * 32 + quad * 8 + 4);
      a[ks].u.x = (uint)f2bf(v0.x) | ((uint)f2bf(v0.y) << 16);
      a[ks].u.y = (uint)f2bf(v0.z) | ((uint)f2bf(v0.w) << 16);
      a[ks].u.z = (uint)f2bf(v1.x) | ((uint)f2bf(v1.y) << 16);
      a[ks].u.w = (uint)f2bf(v1.z) | ((uint)f2bf(v1.w) << 16);
    }
  } else {
    const uint4* A = (const uint4*)Av;
    int row = rbase + n;  // ws rows padded to NNP: in-bounds (values unused for pads)
#pragma unroll
    for (int ks = 0; ks < 4; ++ks) a[ks].u = A[(size_t)row * 16 + ks * 4 + quad];
  }

  f32x4 acc[NT];
#pragma unroll
  for (int tl = 0; tl < NT; ++tl) acc[tl] = (f32x4){0.f, 0.f, 0.f, 0.f};

#pragma unroll
  for (int ks = 0; ks < 4; ++ks) {
#pragma unroll
    for (int tl = 0; tl < NT; ++tl) {
      AB b;
      b.u = *(const uint4*)&Wlds[((ks * NT + tl) * 64 + lane) * 4];
      acc[tl] = __builtin_amdgcn_mfma_f32_16x16x32_bf16(a[ks].s, b.s, acc[tl], 0, 0, 0);
    }
  }

  float4 dv = *(const float4*)(dinv + rbase + quad * 4);
  float dvv[4] = {dv.x, dv.y, dv.z, dv.w};
  unsigned short* ob = Obuf + wv * 16 * COUT;
#pragma unroll
  for (int tl = 0; tl < NT; ++tl)
#pragma unroll
    for (int r = 0; r < 4; ++r)
      ob[(quad * 4 + r) * COUT + tl * 16 + n] = f2bf(acc[tl][r] * dvv[r]);

  // padding rows (>=NN) get explicit zeros -> row NN is a safe zero row for
  // the gathers' clamped loads.
  uint4* gdst = (uint4*)(T + (size_t)rbase * COUT);
  constexpr int ITER = COUT / 32;
#pragma unroll
  for (int i = 0; i < ITER; ++i) {
    int off16 = i * 64 + lane;
    int lrow = (off16 * 8) / COUT;
    uint4 v = make_uint4(0u, 0u, 0u, 0u);
    if (rbase + lrow < NN) v = *(const uint4*)&ob[off16 * 8];
    gdst[off16] = v;
  }
}

// ---------------- gather layers 1/2: XCD channel-sharded ----------------
// slice = blockIdx & 7 (round-robin block->XCD heuristic): each block handles
// 4 nodes x 16 channels (32B row slice) -> per-XCD T working set ~6.4MB lines,
// L2-resident. Wave = 1 node: 16 edge-groups x 4 lanes x uint2, unroll 2.
// Output rows stay row-major; disjoint 32B sector writes are byte-enable safe.
__global__ __launch_bounds__(256) void k_gather12(const int* __restrict__ row_ptr,
                                                  const int* __restrict__ col,
                                                  const char* __restrict__ Tb,
                                                  const float* __restrict__ dinv,
                                                  const float* __restrict__ bias,
                                                  char* __restrict__ Anb) {
  const int slice = blockIdx.x & 7;
  const int node = (blockIdx.x >> 3) * 4 + (threadIdx.x >> 6);
  const int lane = threadIdx.x & 63;
  const int grp = lane >> 2, cl = lane & 3;
  const uint soff = (uint)slice * 32 + (uint)cl * 8;
  int s = row_ptr[node], tend = row_ptr[node + 1];
  float a0 = 0.f, a1 = 0.f, a2 = 0.f, a3 = 0.f;
  if (grp == 0) {  // self-loop term
    uint2 u = *(const uint2*)(Tb + (uint)node * 256 + soff);
    upadd(u.x, a0, a1);
    upadd(u.y, a2, a3);
  }
  const int iters = (tend - s + 31) >> 5;
  const int m = tend - 1;
  int e = s + grp;
  for (int it = 0; it < iters; ++it, e += 32) {
    int i0 = e, i1 = e + 16;
    int c0 = col[min(i0, m)], c1 = col[min(i1, m)];
    c0 = (i0 < tend) ? c0 : NN;  // row NN is all-zero
    c1 = (i1 < tend) ? c1 : NN;
    uint2 v0 = *(const uint2*)(Tb + (uint)c0 * 256 + soff);
    uint2 v1 = *(const uint2*)(Tb + (uint)c1 * 256 + soff);
    upadd(v0.x, a0, a1);
    upadd(v0.y, a2, a3);
    upadd(v1.x, a0, a1);
    upadd(v1.y, a2, a3);
  }
#pragma unroll
  for (int off = 4; off < 64; off <<= 1) {
    a0 += __shfl_down(a0, off, 64);
    a1 += __shfl_down(a1, off, 64);
    a2 += __shfl_down(a2, off, 64);
    a3 += __shfl_down(a3, off, 64);
  }
  if (lane < 4) {
    float4 bb = *(const float4*)&bias[slice * 16 + cl * 4];
    float dv = dinv[node];
    float r0 = fmaxf(fmaf(dv, a0, bb.x), 0.f);
    float r1 = fmaxf(fmaf(dv, a1, bb.y), 0.f);
    float r2 = fmaxf(fmaf(dv, a2, bb.z), 0.f);
    float r3 = fmaxf(fmaf(dv, a3, bb.w), 0.f);
    uint2 o;
    o.x = (uint)f2bf(r0) | ((uint)f2bf(r1) << 16);
    o.y = (uint)f2bf(r2) | ((uint)f2bf(r3) << 16);
    *(uint2*)(Anb + (uint)node * 256 + soff) = o;
  }
}

// ---------------- gather layer 3: uniform-trip clamped, fp32 out ----------
__global__ __launch_bounds__(256) void k_gather3(const int* __restrict__ row_ptr,
                                                 const int* __restrict__ col,
                                                 const uint4* __restrict__ T4,
                                                 float* __restrict__ G3) {
  int w = (blockIdx.x * 256 + threadIdx.x) >> 6;
  int lane = threadIdx.x & 63;
  if (w >= NN) return;
  int s = row_ptr[w], tend = row_ptr[w + 1];
  const int g = lane >> 3;  // edge group 0..7
  const int cl = lane & 7;  // uint4 (8 channels) within 128B row
  float acc[8] = {0.f, 0.f, 0.f, 0.f, 0.f, 0.f, 0.f, 0.f};
  if (g == 0) {
    uint4 u = T4[(size_t)w * 8 + cl];
    upadd(u.x, acc[0], acc[1]);
    upadd(u.y, acc[2], acc[3]);
    upadd(u.z, acc[4], acc[5]);
    upadd(u.w, acc[6], acc[7]);
  }
  const int iters = (tend - s + 15) >> 4;
  const int m = tend - 1;
  int e = s + g;
  for (int it = 0; it < iters; ++it, e += 16) {
    int i0 = e, i1 = e + 8;
    int c0 = col[min(i0, m)], c1 = col[min(i1, m)];
    c0 = (i0 < tend) ? c0 : NN;
    c1 = (i1 < tend) ? c1 : NN;
    uint4 v0 = T4[(size_t)c0 * 8 + cl];
    uint4 v1 = T4[(size_t)c1 * 8 + cl];
    upadd(v0.x, acc[0], acc[1]); upadd(v0.y, acc[2], acc[3]);
    upadd(v0.z, acc[4], acc[5]); upadd(v0.w, acc[6], acc[7]);
    upadd(v1.x, acc[0], acc[1]); upadd(v1.y, acc[2], acc[3]);
    upadd(v1.z, acc[4], acc[5]); upadd(v1.w, acc[6], acc[7]);
  }
#pragma unroll
  for (int i = 0; i < 8; ++i) {
    acc[i] += __shfl_down(acc[i], 8, 64);
    acc[i] += __shfl_down(acc[i], 16, 64);
    acc[i] += __shfl_down(acc[i], 32, 64);
  }
  if (g == 0) {
    float* gp = &G3[(size_t)w * 64 + cl * 8];
    *(float4*)gp = make_float4(acc[0], acc[1], acc[2], acc[3]);
    *(float4*)(gp + 4) = make_float4(acc[4], acc[5], acc[6], acc[7]);
  }
}

// ---------------- pair decode: 4 pairs/wave ----------------
__global__ __launch_bounds__(256) void k_decode(const int* __restrict__ ni,
                                                const int* __restrict__ nj,
                                                const float* __restrict__ G3,
                                                const float* __restrict__ dinv,
                                                const float* __restrict__ b3,
                                                float* __restrict__ out) {
  int p = blockIdx.x * 16 + (threadIdx.x >> 4);
  int cl = threadIdx.x & 15;
  int i = ni[p], j = nj[p];
  float4 gi = *(const float4*)&G3[(size_t)i * 64 + cl * 4];
  float4 gj = *(const float4*)&G3[(size_t)j * 64 + cl * 4];
  float4 bb = *(const float4*)&b3[cl * 4];
  float di = dinv[i], dj = dinv[j];
  float v = fmaf(di, gi.x, bb.x) * fmaf(dj, gj.x, bb.x) +
            fmaf(di, gi.y, bb.y) * fmaf(dj, gj.y, bb.y) +
            fmaf(di, gi.z, bb.z) * fmaf(dj, gj.z, bb.z) +
            fmaf(di, gi.w, bb.w) * fmaf(dj, gj.w, bb.w);
  v += __shfl_xor(v, 1, 64);
  v += __shfl_xor(v, 2, 64);
  v += __shfl_xor(v, 4, 64);
  v += __shfl_xor(v, 8, 64);
  if (cl == 0) out[p] = v;
}

extern "C" void kernel_launch(void* const* d_in, const int* in_sizes, int n_in,
                              void* d_out, int out_size, void* d_ws, size_t ws_size,
                              hipStream_t stream) {
  const float* x  = (const float*)d_in[0];
  const int*   ei = (const int*)d_in[1];
  const int*   ni = (const int*)d_in[2];
  const int*   nj = (const int*)d_in[3];
  const float* W1 = (const float*)d_in[4];
  const float* b1 = (const float*)d_in[5];
  const float* W2 = (const float*)d_in[6];
  const float* b2 = (const float*)d_in[7];
  const float* W3 = (const float*)d_in[8];
  const float* b3 = (const float*)d_in[9];
  float* out = (float*)d_out;

  // ws carve (4-byte words)
  float* dinv    = (float*)d_ws;              // 102400
  int*   row_ptr = (int*)(dinv + 102400);     // 102400 (NN+1 used)
  int*   gcur    = row_ptr + 102400;          // 1024
  int*   col     = gcur + 1024;               // NE
  uint*  Wt1     = (uint*)(col + NE);         // 8192
  uint*  Wt2     = Wt1 + 8192;                // 8192
  uint*  Wt3     = Wt2 + 8192;                // 4096
  uint*  Tbf     = Wt3 + 4096;                // NNP*64 (bf16 [NNP][128])
  uint*  Abf     = Tbf + (size_t)NNP * 64;    // NNP*64
  float* G3      = (float*)(Abf + (size_t)NNP * 64);  // NNP*64 fp32
  int*   aux     = (int*)G3;  // 12.6 MB arena, dead before gather3 writes G3

  // ---- setup (gcur + weight pre-pack) + CSR build ----
  k_setup<<<24, 256, 0, stream>>>(W1, W2, W3, Wt1, Wt2, Wt3, gcur);
  k_bucket<<<(NE + BKB - 1) / BKB, 256, 0, stream>>>(ei, gcur, aux);
  k_csr<<<NBKT, 256, 0, stream>>>(gcur, aux, row_ptr, dinv, col);

  const int GB = NNP / 64;                 // 1563
  const int G12B = (NN / 4) * 8;           // 200000 blocks (4 nodes x 8 slices)
  const int GATB = (NN * 64 + 255) / 256;  // 25000

  // layer 1 (x fp32 -> Tbf bf16)
  k_gemm_mfma<128, true><<<GB, 256, 0, stream>>>(x, Wt1, dinv, (unsigned short*)Tbf);
  k_gather12<<<G12B, 256, 0, stream>>>(row_ptr, col, (const char*)Tbf, dinv, b1, (char*)Abf);
  // layer 2
  k_gemm_mfma<128, false><<<GB, 256, 0, stream>>>(Abf, Wt2, dinv, (unsigned short*)Tbf);
  k_gather12<<<G12B, 256, 0, stream>>>(row_ptr, col, (const char*)Tbf, dinv, b2, (char*)Abf);
  // layer 3 (COUT=64)
  k_gemm_mfma<64, false><<<GB, 256, 0, stream>>>(Abf, Wt3, dinv, (unsigned short*)Tbf);
  k_gather3<<<GATB, 256, 0, stream>>>(row_ptr, col, (const uint4*)Tbf, G3);
  // decode
  k_decode<<<NP / 16, 256, 0, stream>>>(ni, nj, G3, dinv, b3, out);
}

// Round 9
// 379.915 us; speedup vs baseline: 1.8313x; 1.8313x over previous
//
#include <hip/hip_runtime.h>

#define NN 100000
#define NNP 100032   // padded to 1563*64 rows; rows NN..NNP-1 are written as zeros
#define NE 1600000
#define NP 200000
#define NBKT 782     // buckets of 128 nodes
#define BCAP 3072    // per-bucket arena capacity (mean 2046)
#define BKB 4096     // edges per k_bucket block
#define G12H 25000   // gather12 blocks per half (4 nodes/block)

typedef short s16x8 __attribute__((ext_vector_type(8)));
typedef float f32x4 __attribute__((ext_vector_type(4)));

__device__ __forceinline__ unsigned short f2bf(float f) {  // RNE fp32->bf16
  unsigned int u = __float_as_uint(f);
  u += 0x7fffu + ((u >> 16) & 1u);
  return (unsigned short)(u >> 16);
}

__device__ __forceinline__ void upadd(uint u, float& lo, float& hi) {
  lo += __uint_as_float(u << 16);
  hi += __uint_as_float(u & 0xffff0000u);
}

// ---------------- setup: gcur init + W pre-pack, one launch ----------------
template <int NT>
__device__ __forceinline__ void prepw_dev(const float* __restrict__ W,
                                          uint* __restrict__ Wt, int tid) {
  constexpr int COUT = NT * 16;
  if (tid >= 4 * NT * 64) return;
  int lane = tid & 63, comb = tid >> 6;
  int ks = comb / NT, tl = comb % NT;
  int q = lane >> 4, n = lane & 15;
  uint w[4];
#pragma unroll
  for (int jj = 0; jj < 4; ++jj) {
    int k0 = ks * 32 + q * 8 + 2 * jj;
    uint lo = f2bf(W[k0 * COUT + tl * 16 + n]);
    uint hi = f2bf(W[(k0 + 1) * COUT + tl * 16 + n]);
    w[jj] = lo | (hi << 16);
  }
  ((uint4*)Wt)[comb * 64 + lane] = make_uint4(w[0], w[1], w[2], w[3]);
}

__global__ __launch_bounds__(256) void k_setup(const float* __restrict__ W1,
                                               const float* __restrict__ W2,
                                               const float* __restrict__ W3,
                                               uint* __restrict__ Wt1,
                                               uint* __restrict__ Wt2,
                                               uint* __restrict__ Wt3,
                                               int* __restrict__ gcur) {
  int b = blockIdx.x, t = threadIdx.x;
  if (b < 4) {
    int i = b * 256 + t;
    if (i < 1024) gcur[i] = i * BCAP;
  } else if (b < 12) {
    prepw_dev<8>(W1, Wt1, (b - 4) * 256 + t);
  } else if (b < 20) {
    prepw_dev<8>(W2, Wt2, (b - 12) * 256 + t);
  } else {
    prepw_dev<4>(W3, Wt3, (b - 20) * 256 + t);
  }
}

// ---------------- bucket-sort phase A ----------------
__global__ __launch_bounds__(256) void k_bucket(const int* __restrict__ ei,
                                                int* __restrict__ gcur,
                                                int* __restrict__ aux) {
  __shared__ int cnt[1024];
  __shared__ int scn[1024];
  __shared__ int cur[1024];
  __shared__ int sc[256];
  __shared__ int sorted[BKB];
  __shared__ unsigned short sbkt[BKB];
  const int t = threadIdx.x;
  const int base = blockIdx.x * BKB;

  for (int i = t; i < 1024; i += 256) cnt[i] = 0;
  __syncthreads();

  int pk[16], bk[16];
#pragma unroll
  for (int i = 0; i < 16; ++i) {
    int e = base + t + 256 * i;
    if (e < NE) {
      int src = ei[e], dst = ei[NE + e];
      bk[i] = dst >> 7;
      pk[i] = src | ((dst & 127) << 17);
      atomicAdd(&cnt[bk[i]], 1);
    } else {
      bk[i] = -1;
    }
  }
  __syncthreads();

  int s0 = cnt[4 * t], s1 = cnt[4 * t + 1], s2 = cnt[4 * t + 2], s3 = cnt[4 * t + 3];
  int local = s0 + s1 + s2 + s3;
  sc[t] = local;
  __syncthreads();
  for (int off = 1; off < 256; off <<= 1) {
    int a = (t >= off) ? sc[t - off] : 0;
    __syncthreads();
    sc[t] += a;
    __syncthreads();
  }
  int b0 = sc[t] - local;
  scn[4 * t] = b0;
  scn[4 * t + 1] = b0 + s0;
  scn[4 * t + 2] = b0 + s0 + s1;
  scn[4 * t + 3] = b0 + s0 + s1 + s2;
  cur[4 * t] = scn[4 * t];
  cur[4 * t + 1] = scn[4 * t + 1];
  cur[4 * t + 2] = scn[4 * t + 2];
  cur[4 * t + 3] = scn[4 * t + 3];
  __syncthreads();
  const int tot = sc[255];

#pragma unroll
  for (int i = 0; i < 16; ++i) {
    if (bk[i] >= 0) {
      int pos = atomicAdd(&cur[bk[i]], 1);
      sorted[pos] = pk[i];
      sbkt[pos] = (unsigned short)bk[i];
    }
  }
  __syncthreads();

  for (int b = t; b < 1024; b += 256) {
    int c = cnt[b];
    if (c > 0) cur[b] = atomicAdd(&gcur[b], c);
  }
  __syncthreads();

  for (int k = t; k < tot; k += 256) {
    int b = sbkt[k];
    aux[cur[b] + (k - scn[b])] = sorted[k];
  }
}

// ---------------- merged CSR finalize ----------------
__global__ __launch_bounds__(256) void k_csr(const int* __restrict__ gcur,
                                             const int* __restrict__ aux,
                                             int* __restrict__ row_ptr,
                                             float* __restrict__ dinv,
                                             int* __restrict__ col) {
  __shared__ int red[256];
  __shared__ int c[128];
  __shared__ int cur[128];
  const int b = blockIdx.x, t = threadIdx.x;
  int p = 0;
  for (int i = t; i < b; i += 256) p += gcur[i] - i * BCAP;
  red[t] = p;
  if (t < 128) c[t] = 0;
  __syncthreads();
  for (int off = 128; off > 0; off >>= 1) {
    if (t < off) red[t] += red[t + off];
    __syncthreads();
  }
  const int base = red[0];
  const int m = gcur[b] - b * BCAP;
  const int* a = aux + (size_t)b * BCAP;
  __syncthreads();
  for (int k = t; k < m; k += 256) atomicAdd(&c[a[k] >> 17], 1);
  __syncthreads();
  int val = (t < 128) ? c[t] : 0;
  red[t] = val;
  __syncthreads();
  for (int off = 1; off < 128; off <<= 1) {
    int add = (t >= off && t < 128) ? red[t - off] : 0;
    __syncthreads();
    if (t < 128) red[t] += add;
    __syncthreads();
  }
  if (t < 128) {
    int excl = red[t] - val + base;
    int node = b * 128 + t;
    if (node < NN) {
      row_ptr[node] = excl;
      dinv[node] = rsqrtf((float)(val + 1));
      cur[t] = excl;
    }
  }
  if (b == NBKT - 1 && t == 0) row_ptr[NN] = base + m;
  __syncthreads();
  for (int k = t; k < m; k += 256) {
    int pk2 = a[k];
    int pos = atomicAdd(&cur[pk2 >> 17], 1);
    col[pos] = pk2 & 0x1FFFF;
  }
}

// ---------------- MFMA GEMM (padding rows written as zeros) ----------------
template <int COUT, bool AFP32>
__global__ __launch_bounds__(256) void k_gemm_mfma(const void* __restrict__ Av,
                                                   const uint* __restrict__ Wt,
                                                   const float* __restrict__ dinv,
                                                   unsigned short* __restrict__ T) {
  constexpr int NT = COUT / 16;
  __shared__ __align__(16) uint Wlds[4 * NT * 64 * 4];
  __shared__ __align__(16) unsigned short Obuf[64 * COUT];
  const int t = threadIdx.x;
  {
    const uint4* src = (const uint4*)Wt;
    uint4* dst = (uint4*)Wlds;
    for (int i = t; i < 4 * NT * 64; i += 256) dst[i] = src[i];
  }
  __syncthreads();

  const int wv = t >> 6, lane = t & 63;
  const int n = lane & 15, quad = lane >> 4;
  const int rbase = blockIdx.x * 64 + wv * 16;

  union AB { uint4 u; s16x8 s; };
  AB a[4];
  if constexpr (AFP32) {
    const float* A = (const float*)Av;
    int row = rbase + n;
    if (row >= NN) row = NN - 1;  // input x is exactly NN rows
    const float* ap = A + (size_t)row * 128;
#pragma unroll
    for (int ks = 0; ks < 4; ++ks) {
      float4 v0 = *(const float4*)(ap + ks * 32 + quad * 8);
      float4 v1 = *(const float4*)(ap + ks * 32 + quad * 8 + 4);
      a[ks].u.x = (uint)f2bf(v0.x) | ((uint)f2bf(v0.y) << 16);
      a[ks].u.y = (uint)f2bf(v0.z) | ((uint)f2bf(v0.w) << 16);
      a[ks].u.z = (uint)f2bf(v1.x) | ((uint)f2bf(v1.y) << 16);
      a[ks].u.w = (uint)f2bf(v1.z) | ((uint)f2bf(v1.w) << 16);
    }
  } else {
    const uint4* A = (const uint4*)Av;
    int row = rbase + n;  // ws rows padded to NNP: in-bounds (values unused for pads)
#pragma unroll
    for (int ks = 0; ks < 4; ++ks) a[ks].u = A[(size_t)row * 16 + ks * 4 + quad];
  }

  f32x4 acc[NT];
#pragma unroll
  for (int tl = 0; tl < NT; ++tl) acc[tl] = (f32x4){0.f, 0.f, 0.f, 0.f};

#pragma unroll
  for (int ks = 0; ks < 4; ++ks) {
#pragma unroll
    for (int tl = 0; tl < NT; ++tl) {
      AB b;
      b.u = *(const uint4*)&Wlds[((ks * NT + tl) * 64 + lane) * 4];
      acc[tl] = __builtin_amdgcn_mfma_f32_16x16x32_bf16(a[ks].s, b.s, acc[tl], 0, 0, 0);
    }
  }

  float4 dv = *(const float4*)(dinv + rbase + quad * 4);
  float dvv[4] = {dv.x, dv.y, dv.z, dv.w};
  unsigned short* ob = Obuf + wv * 16 * COUT;
#pragma unroll
  for (int tl = 0; tl < NT; ++tl)
#pragma unroll
    for (int r = 0; r < 4; ++r)
      ob[(quad * 4 + r) * COUT + tl * 16 + n] = f2bf(acc[tl][r] * dvv[r]);

  // padding rows (>=NN) get explicit zeros -> row NN is a safe zero row for
  // the gathers' clamped loads.
  uint4* gdst = (uint4*)(T + (size_t)rbase * COUT);
  constexpr int ITER = COUT / 32;
#pragma unroll
  for (int i = 0; i < ITER; ++i) {
    int off16 = i * 64 + lane;
    int lrow = (off16 * 8) / COUT;
    uint4 v = make_uint4(0u, 0u, 0u, 0u);
    if (rbase + lrow < NN) v = *(const uint4*)&ob[off16 * 8];
    gdst[off16] = v;
  }
}

// ---------------- gather layers 1/2: temporal half-split ----------------
// Wave = (node, 64-channel half). Blocks [0,G12H) do half 0, [G12H,2*G12H)
// half 1 -> live T working set is one 12.8MB half shared by ALL XCDs (no
// pinning; reads are 128B-aligned pairs of full lines). 8 edge-groups x
// 8 lanes x uint4, unroll 2 -> 16 row-loads in flight per wave.
__global__ __launch_bounds__(256) void k_gather12(const int* __restrict__ row_ptr,
                                                  const int* __restrict__ col,
                                                  const char* __restrict__ Tb,
                                                  const float* __restrict__ dinv,
                                                  const float* __restrict__ bias,
                                                  char* __restrict__ Anb) {
  const int half = (blockIdx.x >= G12H) ? 1 : 0;
  const int node = (blockIdx.x - half * G12H) * 4 + (threadIdx.x >> 6);
  const int lane = threadIdx.x & 63;
  const int g = lane >> 3;  // edge group 0..7
  const int cl = lane & 7;  // uint4 (8 ch) within 128B half-row
  const uint hoff = (uint)half * 128 + (uint)cl * 16;
  int s = row_ptr[node], tend = row_ptr[node + 1];
  float acc[8] = {0.f, 0.f, 0.f, 0.f, 0.f, 0.f, 0.f, 0.f};
  if (g == 0) {  // self-loop term
    uint4 u = *(const uint4*)(Tb + (uint)node * 256 + hoff);
    upadd(u.x, acc[0], acc[1]);
    upadd(u.y, acc[2], acc[3]);
    upadd(u.z, acc[4], acc[5]);
    upadd(u.w, acc[6], acc[7]);
  }
  const int iters = (tend - s + 15) >> 4;
  const int m = tend - 1;
  int e = s + g;
  for (int it = 0; it < iters; ++it, e += 16) {
    int i0 = e, i1 = e + 8;
    int c0 = col[min(i0, m)], c1 = col[min(i1, m)];
    c0 = (i0 < tend) ? c0 : NN;  // row NN is all-zero
    c1 = (i1 < tend) ? c1 : NN;
    uint4 v0 = *(const uint4*)(Tb + (uint)c0 * 256 + hoff);
    uint4 v1 = *(const uint4*)(Tb + (uint)c1 * 256 + hoff);
    upadd(v0.x, acc[0], acc[1]); upadd(v0.y, acc[2], acc[3]);
    upadd(v0.z, acc[4], acc[5]); upadd(v0.w, acc[6], acc[7]);
    upadd(v1.x, acc[0], acc[1]); upadd(v1.y, acc[2], acc[3]);
    upadd(v1.z, acc[4], acc[5]); upadd(v1.w, acc[6], acc[7]);
  }
#pragma unroll
  for (int i = 0; i < 8; ++i) {
    acc[i] += __shfl_down(acc[i], 8, 64);
    acc[i] += __shfl_down(acc[i], 16, 64);
    acc[i] += __shfl_down(acc[i], 32, 64);
  }
  if (g == 0) {
    const float* bp = bias + half * 64 + cl * 8;
    float4 b0 = *(const float4*)bp;
    float4 b1 = *(const float4*)(bp + 4);
    float dv = dinv[node];
    float r[8];
    r[0] = fmaxf(fmaf(dv, acc[0], b0.x), 0.f);
    r[1] = fmaxf(fmaf(dv, acc[1], b0.y), 0.f);
    r[2] = fmaxf(fmaf(dv, acc[2], b0.z), 0.f);
    r[3] = fmaxf(fmaf(dv, acc[3], b0.w), 0.f);
    r[4] = fmaxf(fmaf(dv, acc[4], b1.x), 0.f);
    r[5] = fmaxf(fmaf(dv, acc[5], b1.y), 0.f);
    r[6] = fmaxf(fmaf(dv, acc[6], b1.z), 0.f);
    r[7] = fmaxf(fmaf(dv, acc[7], b1.w), 0.f);
    uint4 o;
    o.x = (uint)f2bf(r[0]) | ((uint)f2bf(r[1]) << 16);
    o.y = (uint)f2bf(r[2]) | ((uint)f2bf(r[3]) << 16);
    o.z = (uint)f2bf(r[4]) | ((uint)f2bf(r[5]) << 16);
    o.w = (uint)f2bf(r[6]) | ((uint)f2bf(r[7]) << 16);
    *(uint4*)(Anb + (uint)node * 256 + hoff) = o;
  }
}

// ---------------- gather layer 3: uniform-trip clamped, fp32 out ----------
__global__ __launch_bounds__(256) void k_gather3(const int* __restrict__ row_ptr,
                                                 const int* __restrict__ col,
                                                 const uint4* __restrict__ T4,
                                                 float* __restrict__ G3) {
  int w = (blockIdx.x * 256 + threadIdx.x) >> 6;
  int lane = threadIdx.x & 63;
  if (w >= NN) return;
  int s = row_ptr[w], tend = row_ptr[w + 1];
  const int g = lane >> 3;  // edge group 0..7
  const int cl = lane & 7;  // uint4 (8 channels) within 128B row
  float acc[8] = {0.f, 0.f, 0.f, 0.f, 0.f, 0.f, 0.f, 0.f};
  if (g == 0) {
    uint4 u = T4[(size_t)w * 8 + cl];
    upadd(u.x, acc[0], acc[1]);
    upadd(u.y, acc[2], acc[3]);
    upadd(u.z, acc[4], acc[5]);
    upadd(u.w, acc[6], acc[7]);
  }
  const int iters = (tend - s + 15) >> 4;
  const int m = tend - 1;
  int e = s + g;
  for (int it = 0; it < iters; ++it, e += 16) {
    int i0 = e, i1 = e + 8;
    int c0 = col[min(i0, m)], c1 = col[min(i1, m)];
    c0 = (i0 < tend) ? c0 : NN;
    c1 = (i1 < tend) ? c1 : NN;
    uint4 v0 = T4[(size_t)c0 * 8 + cl];
    uint4 v1 = T4[(size_t)c1 * 8 + cl];
    upadd(v0.x, acc[0], acc[1]); upadd(v0.y, acc[2], acc[3]);
    upadd(v0.z, acc[4], acc[5]); upadd(v0.w, acc[6], acc[7]);
    upadd(v1.x, acc[0], acc[1]); upadd(v1.y, acc[2], acc[3]);
    upadd(v1.z, acc[4], acc[5]); upadd(v1.w, acc[6], acc[7]);
  }
#pragma unroll
  for (int i = 0; i < 8; ++i) {
    acc[i] += __shfl_down(acc[i], 8, 64);
    acc[i] += __shfl_down(acc[i], 16, 64);
    acc[i] += __shfl_down(acc[i], 32, 64);
  }
  if (g == 0) {
    float* gp = &G3[(size_t)w * 64 + cl * 8];
    *(float4*)gp = make_float4(acc[0], acc[1], acc[2], acc[3]);
    *(float4*)(gp + 4) = make_float4(acc[4], acc[5], acc[6], acc[7]);
  }
}

// ---------------- pair decode: 4 pairs/wave ----------------
__global__ __launch_bounds__(256) void k_decode(const int* __restrict__ ni,
                                                const int* __restrict__ nj,
                                                const float* __restrict__ G3,
                                                const float* __restrict__ dinv,
                                                const float* __restrict__ b3,
                                                float* __restrict__ out) {
  int p = blockIdx.x * 16 + (threadIdx.x >> 4);
  int cl = threadIdx.x & 15;
  int i = ni[p], j = nj[p];
  float4 gi = *(const float4*)&G3[(size_t)i * 64 + cl * 4];
  float4 gj = *(const float4*)&G3[(size_t)j * 64 + cl * 4];
  float4 bb = *(const float4*)&b3[cl * 4];
  float di = dinv[i], dj = dinv[j];
  float v = fmaf(di, gi.x, bb.x) * fmaf(dj, gj.x, bb.x) +
            fmaf(di, gi.y, bb.y) * fmaf(dj, gj.y, bb.y) +
            fmaf(di, gi.z, bb.z) * fmaf(dj, gj.z, bb.z) +
            fmaf(di, gi.w, bb.w) * fmaf(dj, gj.w, bb.w);
  v += __shfl_xor(v, 1, 64);
  v += __shfl_xor(v, 2, 64);
  v += __shfl_xor(v, 4, 64);
  v += __shfl_xor(v, 8, 64);
  if (cl == 0) out[p] = v;
}

extern "C" void kernel_launch(void* const* d_in, const int* in_sizes, int n_in,
                              void* d_out, int out_size, void* d_ws, size_t ws_size,
                              hipStream_t stream) {
  const float* x  = (const float*)d_in[0];
  const int*   ei = (const int*)d_in[1];
  const int*   ni = (const int*)d_in[2];
  const int*   nj = (const int*)d_in[3];
  const float* W1 = (const float*)d_in[4];
  const float* b1 = (const float*)d_in[5];
  const float* W2 = (const float*)d_in[6];
  const float* b2 = (const float*)d_in[7];
  const float* W3 = (const float*)d_in[8];
  const float* b3 = (const float*)d_in[9];
  float* out = (float*)d_out;

  // ws carve (4-byte words)
  float* dinv    = (float*)d_ws;              // 102400
  int*   row_ptr = (int*)(dinv + 102400);     // 102400 (NN+1 used)
  int*   gcur    = row_ptr + 102400;          // 1024
  int*   col     = gcur + 1024;               // NE
  uint*  Wt1     = (uint*)(col + NE);         // 8192
  uint*  Wt2     = Wt1 + 8192;                // 8192
  uint*  Wt3     = Wt2 + 8192;                // 4096
  uint*  Tbf     = Wt3 + 4096;                // NNP*64 (bf16 [NNP][128])
  uint*  Abf     = Tbf + (size_t)NNP * 64;    // NNP*64
  float* G3      = (float*)(Abf + (size_t)NNP * 64);  // NNP*64 fp32
  int*   aux     = (int*)G3;  // 12.6 MB arena, dead before gather3 writes G3

  // ---- setup (gcur + weight pre-pack) + CSR build ----
  k_setup<<<24, 256, 0, stream>>>(W1, W2, W3, Wt1, Wt2, Wt3, gcur);
  k_bucket<<<(NE + BKB - 1) / BKB, 256, 0, stream>>>(ei, gcur, aux);
  k_csr<<<NBKT, 256, 0, stream>>>(gcur, aux, row_ptr, dinv, col);

  const int GB = NNP / 64;                 // 1563
  const int GATB = (NN * 64 + 255) / 256;  // 25000

  // layer 1 (x fp32 -> Tbf bf16)
  k_gemm_mfma<128, true><<<GB, 256, 0, stream>>>(x, Wt1, dinv, (unsigned short*)Tbf);
  k_gather12<<<2 * G12H, 256, 0, stream>>>(row_ptr, col, (const char*)Tbf, dinv, b1, (char*)Abf);
  // layer 2
  k_gemm_mfma<128, false><<<GB, 256, 0, stream>>>(Abf, Wt2, dinv, (unsigned short*)Tbf);
  k_gather12<<<2 * G12H, 256, 0, stream>>>(row_ptr, col, (const char*)Tbf, dinv, b2, (char*)Abf);
  // layer 3 (COUT=64)
  k_gemm_mfma<64, false><<<GB, 256, 0, stream>>>(Abf, Wt3, dinv, (unsigned short*)Tbf);
  k_gather3<<<GATB, 256, 0, stream>>>(row_ptr, col, (const uint4*)Tbf, G3);
  // decode
  k_decode<<<NP / 16, 256, 0, stream>>>(ni, nj, G3, dinv, b3, out);
}

// Round 10
// 364.780 us; speedup vs baseline: 1.9073x; 1.0415x over previous
//
#include <hip/hip_runtime.h>

#define NN 100000
#define NNP 100032   // 6252*16 rows; rows NN..NNP-1 are zero
#define NE 1600000
#define NP 200000
#define NBKT 782
#define BCAP 3072
#define BKB 4096

typedef short s16x8 __attribute__((ext_vector_type(8)));
typedef float f32x4 __attribute__((ext_vector_type(4)));

__device__ __forceinline__ unsigned short f2bf(float f) {  // RNE fp32->bf16
  unsigned int u = __float_as_uint(f);
  u += 0x7fffu + ((u >> 16) & 1u);
  return (unsigned short)(u >> 16);
}

__device__ __forceinline__ void upadd(uint u, float& lo, float& hi) {
  lo += __uint_as_float(u << 16);
  hi += __uint_as_float(u & 0xffff0000u);
}

// ---------------- setup: gcur init + W pre-pack ----------------
template <int NT>
__device__ __forceinline__ void prepw_dev(const float* __restrict__ W,
                                          uint* __restrict__ Wt, int tid) {
  constexpr int COUT = NT * 16;
  if (tid >= 4 * NT * 64) return;
  int lane = tid & 63, comb = tid >> 6;
  int ks = comb / NT, tl = comb % NT;
  int q = lane >> 4, n = lane & 15;
  uint w[4];
#pragma unroll
  for (int jj = 0; jj < 4; ++jj) {
    int k0 = ks * 32 + q * 8 + 2 * jj;
    uint lo = f2bf(W[k0 * COUT + tl * 16 + n]);
    uint hi = f2bf(W[(k0 + 1) * COUT + tl * 16 + n]);
    w[jj] = lo | (hi << 16);
  }
  ((uint4*)Wt)[comb * 64 + lane] = make_uint4(w[0], w[1], w[2], w[3]);
}

__global__ __launch_bounds__(256) void k_setup(const float* __restrict__ W1,
                                               const float* __restrict__ W2,
                                               const float* __restrict__ W3,
                                               uint* __restrict__ Wt1,
                                               uint* __restrict__ Wt2,
                                               uint* __restrict__ Wt3,
                                               int* __restrict__ gcur) {
  int b = blockIdx.x, t = threadIdx.x;
  if (b < 4) {
    int i = b * 256 + t;
    if (i < 1024) gcur[i] = i * BCAP;
  } else if (b < 12) {
    prepw_dev<8>(W1, Wt1, (b - 4) * 256 + t);
  } else if (b < 20) {
    prepw_dev<8>(W2, Wt2, (b - 12) * 256 + t);
  } else {
    prepw_dev<4>(W3, Wt3, (b - 20) * 256 + t);
  }
}

// ---------------- bucket-sort phase A ----------------
__global__ __launch_bounds__(256) void k_bucket(const int* __restrict__ ei,
                                                int* __restrict__ gcur,
                                                int* __restrict__ aux) {
  __shared__ int cnt[1024];
  __shared__ int scn[1024];
  __shared__ int cur[1024];
  __shared__ int sc[256];
  __shared__ int sorted[BKB];
  __shared__ unsigned short sbkt[BKB];
  const int t = threadIdx.x;
  const int base = blockIdx.x * BKB;

  for (int i = t; i < 1024; i += 256) cnt[i] = 0;
  __syncthreads();

  int pk[16], bk[16];
#pragma unroll
  for (int i = 0; i < 16; ++i) {
    int e = base + t + 256 * i;
    if (e < NE) {
      int src = ei[e], dst = ei[NE + e];
      bk[i] = dst >> 7;
      pk[i] = src | ((dst & 127) << 17);
      atomicAdd(&cnt[bk[i]], 1);
    } else {
      bk[i] = -1;
    }
  }
  __syncthreads();

  int s0 = cnt[4 * t], s1 = cnt[4 * t + 1], s2 = cnt[4 * t + 2], s3 = cnt[4 * t + 3];
  int local = s0 + s1 + s2 + s3;
  sc[t] = local;
  __syncthreads();
  for (int off = 1; off < 256; off <<= 1) {
    int a = (t >= off) ? sc[t - off] : 0;
    __syncthreads();
    sc[t] += a;
    __syncthreads();
  }
  int b0 = sc[t] - local;
  scn[4 * t] = b0;
  scn[4 * t + 1] = b0 + s0;
  scn[4 * t + 2] = b0 + s0 + s1;
  scn[4 * t + 3] = b0 + s0 + s1 + s2;
  cur[4 * t] = scn[4 * t];
  cur[4 * t + 1] = scn[4 * t + 1];
  cur[4 * t + 2] = scn[4 * t + 2];
  cur[4 * t + 3] = scn[4 * t + 3];
  __syncthreads();
  const int tot = sc[255];

#pragma unroll
  for (int i = 0; i < 16; ++i) {
    if (bk[i] >= 0) {
      int pos = atomicAdd(&cur[bk[i]], 1);
      sorted[pos] = pk[i];
      sbkt[pos] = (unsigned short)bk[i];
    }
  }
  __syncthreads();

  for (int b = t; b < 1024; b += 256) {
    int c = cnt[b];
    if (c > 0) cur[b] = atomicAdd(&gcur[b], c);
  }
  __syncthreads();

  for (int k = t; k < tot; k += 256) {
    int b = sbkt[k];
    aux[cur[b] + (k - scn[b])] = sorted[k];
  }
}

// ---------------- merged CSR finalize ----------------
__global__ __launch_bounds__(256) void k_csr(const int* __restrict__ gcur,
                                             const int* __restrict__ aux,
                                             int* __restrict__ row_ptr,
                                             float* __restrict__ dinv,
                                             int* __restrict__ col) {
  __shared__ int red[256];
  __shared__ int c[128];
  __shared__ int cur[128];
  const int b = blockIdx.x, t = threadIdx.x;
  int p = 0;
  for (int i = t; i < b; i += 256) p += gcur[i] - i * BCAP;
  red[t] = p;
  if (t < 128) c[t] = 0;
  __syncthreads();
  for (int off = 128; off > 0; off >>= 1) {
    if (t < off) red[t] += red[t + off];
    __syncthreads();
  }
  const int base = red[0];
  const int m = gcur[b] - b * BCAP;
  const int* a = aux + (size_t)b * BCAP;
  __syncthreads();
  for (int k = t; k < m; k += 256) atomicAdd(&c[a[k] >> 17], 1);
  __syncthreads();
  int val = (t < 128) ? c[t] : 0;
  red[t] = val;
  __syncthreads();
  for (int off = 1; off < 128; off <<= 1) {
    int add = (t >= off && t < 128) ? red[t - off] : 0;
    __syncthreads();
    if (t < 128) red[t] += add;
    __syncthreads();
  }
  if (t < 128) {
    int excl = red[t] - val + base;
    int node = b * 128 + t;
    if (node < NN) {
      row_ptr[node] = excl;
      dinv[node] = rsqrtf((float)(val + 1));
      cur[t] = excl;
    }
  }
  if (b == NBKT - 1 && t == 0) row_ptr[NN] = base + m;
  __syncthreads();
  for (int k = t; k < m; k += 256) {
    int pk2 = a[k];
    int pos = atomicAdd(&cur[pk2 >> 17], 1);
    col[pos] = pk2 & 0x1FFFF;
  }
}

// ---------------- MFMA GEMM for layer 1 (x fp32 -> T1 bf16) ----------------
__global__ __launch_bounds__(256) void k_gemm1(const float* __restrict__ A,
                                               const uint* __restrict__ Wt,
                                               const float* __restrict__ dinv,
                                               unsigned short* __restrict__ T) {
  constexpr int NT = 8, COUT = 128;
  __shared__ __align__(16) uint Wlds[4 * NT * 64 * 4];
  __shared__ __align__(16) unsigned short Obuf[64 * COUT];
  const int t = threadIdx.x;
  {
    const uint4* src = (const uint4*)Wt;
    uint4* dst = (uint4*)Wlds;
    for (int i = t; i < 4 * NT * 64; i += 256) dst[i] = src[i];
  }
  __syncthreads();

  const int wv = t >> 6, lane = t & 63;
  const int n = lane & 15, quad = lane >> 4;
  const int rbase = blockIdx.x * 64 + wv * 16;

  union AB { uint4 u; s16x8 s; };
  AB a[4];
  {
    int row = rbase + n;
    if (row >= NN) row = NN - 1;
    const float* ap = A + (size_t)row * 128;
#pragma unroll
    for (int ks = 0; ks < 4; ++ks) {
      float4 v0 = *(const float4*)(ap + ks * 32 + quad * 8);
      float4 v1 = *(const float4*)(ap + ks * 32 + quad * 8 + 4);
      a[ks].u.x = (uint)f2bf(v0.x) | ((uint)f2bf(v0.y) << 16);
      a[ks].u.y = (uint)f2bf(v0.z) | ((uint)f2bf(v0.w) << 16);
      a[ks].u.z = (uint)f2bf(v1.x) | ((uint)f2bf(v1.y) << 16);
      a[ks].u.w = (uint)f2bf(v1.z) | ((uint)f2bf(v1.w) << 16);
    }
  }

  f32x4 acc[NT];
#pragma unroll
  for (int tl = 0; tl < NT; ++tl) acc[tl] = (f32x4){0.f, 0.f, 0.f, 0.f};

#pragma unroll
  for (int ks = 0; ks < 4; ++ks) {
#pragma unroll
    for (int tl = 0; tl < NT; ++tl) {
      AB b;
      b.u = *(const uint4*)&Wlds[((ks * NT + tl) * 64 + lane) * 4];
      acc[tl] = __builtin_amdgcn_mfma_f32_16x16x32_bf16(a[ks].s, b.s, acc[tl], 0, 0, 0);
    }
  }

  float4 dv = *(const float4*)(dinv + rbase + quad * 4);
  float dvv[4] = {dv.x, dv.y, dv.z, dv.w};
  unsigned short* ob = Obuf + wv * 16 * COUT;
#pragma unroll
  for (int tl = 0; tl < NT; ++tl)
#pragma unroll
    for (int r = 0; r < 4; ++r)
      ob[(quad * 4 + r) * COUT + tl * 16 + n] = f2bf(acc[tl][r] * dvv[r]);

  uint4* gdst = (uint4*)(T + (size_t)rbase * COUT);
#pragma unroll
  for (int i = 0; i < 4; ++i) {
    int off16 = i * 64 + lane;
    int lrow = (off16 * 8) / COUT;
    uint4 v = make_uint4(0u, 0u, 0u, 0u);
    if (rbase + lrow < NN) v = *(const uint4*)&ob[off16 * 8];
    gdst[off16] = v;
  }
}

// ---------------- fused gather + GEMM (layers 2 and 3) ----------------
// Block = 16 nodes. Phase 1: each of 4 waves runs 4 sequential R7-style
// node-gathers over Tin (bf16 256B rows) with uniform-trip clamped loop,
// epilogue relu(dinv*agg+bias) -> bf16 A-row into padded LDS. Phase 2:
// 16x128 @ 128xCOUT MFMA from LDS A-frags + LDS W, scale by dinv, write
// Tout (rows >= NN zeroed).
template <int COUT>
__global__ __launch_bounds__(256) void k_gagemm(const int* __restrict__ row_ptr,
                                                const int* __restrict__ col,
                                                const char* __restrict__ Tin,
                                                const float* __restrict__ dinv,
                                                const float* __restrict__ bias,
                                                const uint* __restrict__ Wt,
                                                unsigned short* __restrict__ Tout) {
  constexpr int NT = COUT / 16;   // 8 or 4
  constexpr int TLW = NT / 4;     // col-tiles per wave: 2 or 1
  constexpr int OSTR = COUT + 8;  // Obuf row stride (ushorts)
  __shared__ __align__(16) uint Wlds[4 * NT * 64 * 4];
  __shared__ __align__(16) uint4 Alds[16 * 17];  // 16 rows x (16 uint4 + 1 pad)
  __shared__ __align__(16) unsigned short Obuf[16 * OSTR];
  const int t = threadIdx.x;
  {
    const uint4* src = (const uint4*)Wt;
    uint4* dst = (uint4*)Wlds;
    for (int i = t; i < 4 * NT * 64; i += 256) dst[i] = src[i];
  }

  const int wv = t >> 6, lane = t & 63;
  const int nbase = blockIdx.x * 16;
  const int q = lane >> 4, cl = lane & 15;

  // ---- phase 1: gather 4 nodes per wave ----
#pragma unroll 1
  for (int i = 0; i < 4; ++i) {
    const int node = nbase + wv * 4 + i;
    int s = 0, tend = 0;
    if (node < NN) { s = row_ptr[node]; tend = row_ptr[node + 1]; }
    float acc[8] = {0.f, 0.f, 0.f, 0.f, 0.f, 0.f, 0.f, 0.f};
    if (q == 0) {  // self-loop term (zero row for pads)
      uint4 u = *(const uint4*)(Tin + (uint)node * 256 + cl * 16);
      upadd(u.x, acc[0], acc[1]);
      upadd(u.y, acc[2], acc[3]);
      upadd(u.z, acc[4], acc[5]);
      upadd(u.w, acc[6], acc[7]);
    }
    const int iters = (tend - s + 15) >> 4;
    const int m = tend - 1;
    int e = s + q;
    for (int it = 0; it < iters; ++it, e += 16) {
      int i0 = e, i1 = e + 4, i2 = e + 8, i3 = e + 12;
      int c0 = col[min(i0, m)], c1 = col[min(i1, m)];
      int c2 = col[min(i2, m)], c3 = col[min(i3, m)];
      c0 = (i0 < tend) ? c0 : NN;  // row NN is all-zero
      c1 = (i1 < tend) ? c1 : NN;
      c2 = (i2 < tend) ? c2 : NN;
      c3 = (i3 < tend) ? c3 : NN;
      uint4 v0 = *(const uint4*)(Tin + (uint)c0 * 256 + cl * 16);
      uint4 v1 = *(const uint4*)(Tin + (uint)c1 * 256 + cl * 16);
      uint4 v2 = *(const uint4*)(Tin + (uint)c2 * 256 + cl * 16);
      uint4 v3 = *(const uint4*)(Tin + (uint)c3 * 256 + cl * 16);
      upadd(v0.x, acc[0], acc[1]); upadd(v0.y, acc[2], acc[3]);
      upadd(v0.z, acc[4], acc[5]); upadd(v0.w, acc[6], acc[7]);
      upadd(v1.x, acc[0], acc[1]); upadd(v1.y, acc[2], acc[3]);
      upadd(v1.z, acc[4], acc[5]); upadd(v1.w, acc[6], acc[7]);
      upadd(v2.x, acc[0], acc[1]); upadd(v2.y, acc[2], acc[3]);
      upadd(v2.z, acc[4], acc[5]); upadd(v2.w, acc[6], acc[7]);
      upadd(v3.x, acc[0], acc[1]); upadd(v3.y, acc[2], acc[3]);
      upadd(v3.z, acc[4], acc[5]); upadd(v3.w, acc[6], acc[7]);
    }
#pragma unroll
    for (int k = 0; k < 8; ++k) {
      acc[k] += __shfl_down(acc[k], 16, 64);
      acc[k] += __shfl_down(acc[k], 32, 64);
    }
    if (q == 0) {
      float4 b0 = *(const float4*)&bias[cl * 8];
      float4 b1 = *(const float4*)&bias[cl * 8 + 4];
      float dv = dinv[node];  // pad nodes: finite garbage, rows zeroed later
      float r[8];
      r[0] = fmaxf(fmaf(dv, acc[0], b0.x), 0.f);
      r[1] = fmaxf(fmaf(dv, acc[1], b0.y), 0.f);
      r[2] = fmaxf(fmaf(dv, acc[2], b0.z), 0.f);
      r[3] = fmaxf(fmaf(dv, acc[3], b0.w), 0.f);
      r[4] = fmaxf(fmaf(dv, acc[4], b1.x), 0.f);
      r[5] = fmaxf(fmaf(dv, acc[5], b1.y), 0.f);
      r[6] = fmaxf(fmaf(dv, acc[6], b1.z), 0.f);
      r[7] = fmaxf(fmaf(dv, acc[7], b1.w), 0.f);
      uint4 o;
      o.x = (uint)f2bf(r[0]) | ((uint)f2bf(r[1]) << 16);
      o.y = (uint)f2bf(r[2]) | ((uint)f2bf(r[3]) << 16);
      o.z = (uint)f2bf(r[4]) | ((uint)f2bf(r[5]) << 16);
      o.w = (uint)f2bf(r[6]) | ((uint)f2bf(r[7]) << 16);
      Alds[(wv * 4 + i) * 17 + cl] = o;
    }
  }
  __syncthreads();

  // ---- phase 2: MFMA 16x128 @ 128xCOUT ----
  const int n = lane & 15, quad = lane >> 4;
  union AB { uint4 u; s16x8 s; };
  f32x4 acc2[TLW];
#pragma unroll
  for (int j = 0; j < TLW; ++j) acc2[j] = (f32x4){0.f, 0.f, 0.f, 0.f};
#pragma unroll
  for (int ks = 0; ks < 4; ++ks) {
    AB a;
    a.u = Alds[n * 17 + ks * 4 + quad];
#pragma unroll
    for (int j = 0; j < TLW; ++j) {
      int tl = wv * TLW + j;
      AB b;
      b.u = *(const uint4*)&Wlds[((ks * NT + tl) * 64 + lane) * 4];
      acc2[j] = __builtin_amdgcn_mfma_f32_16x16x32_bf16(a.s, b.s, acc2[j], 0, 0, 0);
    }
  }

  float4 dv4 = *(const float4*)(dinv + nbase + quad * 4);
  float dvv[4] = {dv4.x, dv4.y, dv4.z, dv4.w};
#pragma unroll
  for (int j = 0; j < TLW; ++j) {
    int tl = wv * TLW + j;
#pragma unroll
    for (int r = 0; r < 4; ++r)
      Obuf[(quad * 4 + r) * OSTR + tl * 16 + n] = f2bf(acc2[j][r] * dvv[r]);
  }
  __syncthreads();

  // coalesced Tout write; rows >= NN zeroed (keeps zero-row invariant)
  if constexpr (COUT == 128) {
    int lrow = lane >> 4 | (wv << 2);     // 0..15 across 256 threads? no:
    // 256 lanes: tile = 16 rows x 16 uint4. thread t -> row t>>4, col t&15.
    int row = t >> 4, c16 = t & 15;
    uint4 v = make_uint4(0u, 0u, 0u, 0u);
    if (nbase + row < NN) v = *(const uint4*)&Obuf[row * OSTR + c16 * 8];
    ((uint4*)(Tout + (size_t)nbase * COUT))[row * 16 + c16] = v;
    (void)lrow;
  } else {
    // tile = 16 rows x 8 uint4 = 128 threads
    if (t < 128) {
      int row = t >> 3, c16 = t & 7;
      uint4 v = make_uint4(0u, 0u, 0u, 0u);
      if (nbase + row < NN) v = *(const uint4*)&Obuf[row * OSTR + c16 * 8];
      ((uint4*)(Tout + (size_t)nbase * COUT))[row * 8 + c16] = v;
    }
  }
}

// ---------------- gather layer 3: uniform-trip clamped, fp32 out ----------
__global__ __launch_bounds__(256) void k_gather3(const int* __restrict__ row_ptr,
                                                 const int* __restrict__ col,
                                                 const uint4* __restrict__ T4,
                                                 float* __restrict__ G3) {
  int w = (blockIdx.x * 256 + threadIdx.x) >> 6;
  int lane = threadIdx.x & 63;
  if (w >= NN) return;
  int s = row_ptr[w], tend = row_ptr[w + 1];
  const int g = lane >> 3;  // edge group 0..7
  const int cl = lane & 7;  // uint4 (8 channels) within 128B row
  float acc[8] = {0.f, 0.f, 0.f, 0.f, 0.f, 0.f, 0.f, 0.f};
  if (g == 0) {
    uint4 u = T4[(size_t)w * 8 + cl];
    upadd(u.x, acc[0], acc[1]);
    upadd(u.y, acc[2], acc[3]);
    upadd(u.z, acc[4], acc[5]);
    upadd(u.w, acc[6], acc[7]);
  }
  const int iters = (tend - s + 15) >> 4;
  const int m = tend - 1;
  int e = s + g;
  for (int it = 0; it < iters; ++it, e += 16) {
    int i0 = e, i1 = e + 8;
    int c0 = col[min(i0, m)], c1 = col[min(i1, m)];
    c0 = (i0 < tend) ? c0 : NN;
    c1 = (i1 < tend) ? c1 : NN;
    uint4 v0 = T4[(size_t)c0 * 8 + cl];
    uint4 v1 = T4[(size_t)c1 * 8 + cl];
    upadd(v0.x, acc[0], acc[1]); upadd(v0.y, acc[2], acc[3]);
    upadd(v0.z, acc[4], acc[5]); upadd(v0.w, acc[6], acc[7]);
    upadd(v1.x, acc[0], acc[1]); upadd(v1.y, acc[2], acc[3]);
    upadd(v1.z, acc[4], acc[5]); upadd(v1.w, acc[6], acc[7]);
  }
#pragma unroll
  for (int i = 0; i < 8; ++i) {
    acc[i] += __shfl_down(acc[i], 8, 64);
    acc[i] += __shfl_down(acc[i], 16, 64);
    acc[i] += __shfl_down(acc[i], 32, 64);
  }
  if (g == 0) {
    float* gp = &G3[(size_t)w * 64 + cl * 8];
    *(float4*)gp = make_float4(acc[0], acc[1], acc[2], acc[3]);
    *(float4*)(gp + 4) = make_float4(acc[4], acc[5], acc[6], acc[7]);
  }
}

// ---------------- pair decode: 4 pairs/wave ----------------
__global__ __launch_bounds__(256) void k_decode(const int* __restrict__ ni,
                                                const int* __restrict__ nj,
                                                const float* __restrict__ G3,
                                                const float* __restrict__ dinv,
                                                const float* __restrict__ b3,
                                                float* __restrict__ out) {
  int p = blockIdx.x * 16 + (threadIdx.x >> 4);
  int cl = threadIdx.x & 15;
  int i = ni[p], j = nj[p];
  float4 gi = *(const float4*)&G3[(size_t)i * 64 + cl * 4];
  float4 gj = *(const float4*)&G3[(size_t)j * 64 + cl * 4];
  float4 bb = *(const float4*)&b3[cl * 4];
  float di = dinv[i], dj = dinv[j];
  float v = fmaf(di, gi.x, bb.x) * fmaf(dj, gj.x, bb.x) +
            fmaf(di, gi.y, bb.y) * fmaf(dj, gj.y, bb.y) +
            fmaf(di, gi.z, bb.z) * fmaf(dj, gj.z, bb.z) +
            fmaf(di, gi.w, bb.w) * fmaf(dj, gj.w, bb.w);
  v += __shfl_xor(v, 1, 64);
  v += __shfl_xor(v, 2, 64);
  v += __shfl_xor(v, 4, 64);
  v += __shfl_xor(v, 8, 64);
  if (cl == 0) out[p] = v;
}

extern "C" void kernel_launch(void* const* d_in, const int* in_sizes, int n_in,
                              void* d_out, int out_size, void* d_ws, size_t ws_size,
                              hipStream_t stream) {
  const float* x  = (const float*)d_in[0];
  const int*   ei = (const int*)d_in[1];
  const int*   ni = (const int*)d_in[2];
  const int*   nj = (const int*)d_in[3];
  const float* W1 = (const float*)d_in[4];
  const float* b1 = (const float*)d_in[5];
  const float* W2 = (const float*)d_in[6];
  const float* b2 = (const float*)d_in[7];
  const float* W3 = (const float*)d_in[8];
  const float* b3 = (const float*)d_in[9];
  float* out = (float*)d_out;

  // ws carve (4-byte words)
  float* dinv    = (float*)d_ws;              // 102400
  int*   row_ptr = (int*)(dinv + 102400);     // 102400 (NN+1 used)
  int*   gcur    = row_ptr + 102400;          // 1024
  int*   col     = gcur + 1024;               // NE
  uint*  Wt1     = (uint*)(col + NE);         // 8192
  uint*  Wt2     = Wt1 + 8192;                // 8192
  uint*  Wt3     = Wt2 + 8192;                // 4096
  uint*  Tbf     = Wt3 + 4096;                // NNP*64: T1, later T3
  uint*  T2      = Tbf + (size_t)NNP * 64;    // NNP*64
  float* G3      = (float*)(T2 + (size_t)NNP * 64);  // NNP*64 fp32
  int*   aux     = (int*)G3;  // 12.6 MB arena, dead before gather3 writes G3

  // ---- setup (gcur + weight pre-pack) + CSR build ----
  k_setup<<<24, 256, 0, stream>>>(W1, W2, W3, Wt1, Wt2, Wt3, gcur);
  k_bucket<<<(NE + BKB - 1) / BKB, 256, 0, stream>>>(ei, gcur, aux);
  k_csr<<<NBKT, 256, 0, stream>>>(gcur, aux, row_ptr, dinv, col);

  const int GB = NNP / 64;                 // 1563
  const int FB = NNP / 16;                 // 6252
  const int GATB = (NN * 64 + 255) / 256;  // 25000

  // layer 1 (x fp32 -> T1 bf16)
  k_gemm1<<<GB, 256, 0, stream>>>(x, Wt1, dinv, (unsigned short*)Tbf);
  // layer 2: fused gather(T1)+epilogue(b1)+GEMM(W2) -> T2
  k_gagemm<128><<<FB, 256, 0, stream>>>(row_ptr, col, (const char*)Tbf, dinv, b1,
                                        Wt2, (unsigned short*)T2);
  // layer 3: fused gather(T2)+epilogue(b2)+GEMM(W3) -> T3 (reuses Tbf)
  k_gagemm<64><<<FB, 256, 0, stream>>>(row_ptr, col, (const char*)T2, dinv, b2,
                                       Wt3, (unsigned short*)Tbf);
  // final aggregation (T3 -> G3 fp32)
  k_gather3<<<GATB, 256, 0, stream>>>(row_ptr, col, (const uint4*)Tbf, G3);
  // decode
  k_decode<<<NP / 16, 256, 0, stream>>>(ni, nj, G3, dinv, b3, out);
}

// Round 11
// 339.564 us; speedup vs baseline: 2.0489x; 1.0743x over previous
//
#include <hip/hip_runtime.h>

#define NN 100000
#define NNP 100032   // padded rows; rows NN..NNP-1 of T buffers are zero
#define NE 1600000
#define NP 200000
#define NBKT 782
#define BCAP 3072
#define BKB 4096

typedef short s16x8 __attribute__((ext_vector_type(8)));
typedef float f32x4 __attribute__((ext_vector_type(4)));

__device__ __forceinline__ unsigned short f2bf(float f) {  // RNE fp32->bf16
  unsigned int u = __float_as_uint(f);
  u += 0x7fffu + ((u >> 16) & 1u);
  return (unsigned short)(u >> 16);
}

__device__ __forceinline__ void upadd(uint u, float& lo, float& hi) {
  lo += __uint_as_float(u << 16);
  hi += __uint_as_float(u & 0xffff0000u);
}

// ---------------- setup: gcur zero + W pre-pack ----------------
template <int NT>
__device__ __forceinline__ void prepw_dev(const float* __restrict__ W,
                                          uint* __restrict__ Wt, int tid) {
  constexpr int COUT = NT * 16;
  if (tid >= 4 * NT * 64) return;
  int lane = tid & 63, comb = tid >> 6;
  int ks = comb / NT, tl = comb % NT;
  int q = lane >> 4, n = lane & 15;
  uint w[4];
#pragma unroll
  for (int jj = 0; jj < 4; ++jj) {
    int k0 = ks * 32 + q * 8 + 2 * jj;
    uint lo = f2bf(W[k0 * COUT + tl * 16 + n]);
    uint hi = f2bf(W[(k0 + 1) * COUT + tl * 16 + n]);
    w[jj] = lo | (hi << 16);
  }
  ((uint4*)Wt)[comb * 64 + lane] = make_uint4(w[0], w[1], w[2], w[3]);
}

__global__ __launch_bounds__(256) void k_setup(const float* __restrict__ W1,
                                               const float* __restrict__ W2,
                                               const float* __restrict__ W3,
                                               uint* __restrict__ Wt1,
                                               uint* __restrict__ Wt2,
                                               uint* __restrict__ Wt3,
                                               int* __restrict__ gcur) {
  int b = blockIdx.x, t = threadIdx.x;
  if (b < 4) {
    int i = b * 256 + t;
    if (i < 1024) gcur[i] = 0;
  } else if (b < 12) {
    prepw_dev<8>(W1, Wt1, (b - 4) * 256 + t);
  } else if (b < 20) {
    prepw_dev<8>(W2, Wt2, (b - 12) * 256 + t);
  } else {
    prepw_dev<4>(W3, Wt3, (b - 20) * 256 + t);
  }
}

// ---------------- bucket-sort phase A ----------------
__global__ __launch_bounds__(256) void k_bucket(const int* __restrict__ ei,
                                                int* __restrict__ gcur,
                                                int* __restrict__ aux) {
  __shared__ int cnt[1024];
  __shared__ int scn[1024];
  __shared__ int cur[1024];
  __shared__ int sc[256];
  __shared__ int sorted[BKB];
  __shared__ unsigned short sbkt[BKB];
  const int t = threadIdx.x;
  const int base = blockIdx.x * BKB;

  for (int i = t; i < 1024; i += 256) cnt[i] = 0;
  __syncthreads();

  int pk[16], bk[16];
#pragma unroll
  for (int i = 0; i < 16; ++i) {
    int e = base + t + 256 * i;
    if (e < NE) {
      int src = ei[e], dst = ei[NE + e];
      bk[i] = dst >> 7;
      pk[i] = src | ((dst & 127) << 17);
      atomicAdd(&cnt[bk[i]], 1);
    } else {
      bk[i] = -1;
    }
  }
  __syncthreads();

  int s0 = cnt[4 * t], s1 = cnt[4 * t + 1], s2 = cnt[4 * t + 2], s3 = cnt[4 * t + 3];
  int local = s0 + s1 + s2 + s3;
  sc[t] = local;
  __syncthreads();
  for (int off = 1; off < 256; off <<= 1) {
    int a = (t >= off) ? sc[t - off] : 0;
    __syncthreads();
    sc[t] += a;
    __syncthreads();
  }
  int b0 = sc[t] - local;
  scn[4 * t] = b0;
  scn[4 * t + 1] = b0 + s0;
  scn[4 * t + 2] = b0 + s0 + s1;
  scn[4 * t + 3] = b0 + s0 + s1 + s2;
  cur[4 * t] = scn[4 * t];
  cur[4 * t + 1] = scn[4 * t + 1];
  cur[4 * t + 2] = scn[4 * t + 2];
  cur[4 * t + 3] = scn[4 * t + 3];
  __syncthreads();
  const int tot = sc[255];

#pragma unroll
  for (int i = 0; i < 16; ++i) {
    if (bk[i] >= 0) {
      int pos = atomicAdd(&cur[bk[i]], 1);
      sorted[pos] = pk[i];
      sbkt[pos] = (unsigned short)bk[i];
    }
  }
  __syncthreads();

  // gcur holds RELATIVE counts; arena base is b*BCAP
  for (int b = t; b < 1024; b += 256) {
    int c = cnt[b];
    if (c > 0) cur[b] = b * BCAP + atomicAdd(&gcur[b], c);
  }
  __syncthreads();

  for (int k = t; k < tot; k += 256) {
    int b = sbkt[k];
    aux[cur[b] + (k - scn[b])] = sorted[k];
  }
}

// ---------------- merged CSR finalize ----------------
__global__ __launch_bounds__(256) void k_csr(const int* __restrict__ gcur,
                                             const int* __restrict__ aux,
                                             int* __restrict__ row_ptr,
                                             float* __restrict__ dinv,
                                             int* __restrict__ col) {
  __shared__ int red[256];
  __shared__ int c[128];
  __shared__ int cur[128];
  const int b = blockIdx.x, t = threadIdx.x;
  int p = 0;
  for (int i = t; i < b; i += 256) p += gcur[i];
  red[t] = p;
  if (t < 128) c[t] = 0;
  __syncthreads();
  for (int off = 128; off > 0; off >>= 1) {
    if (t < off) red[t] += red[t + off];
    __syncthreads();
  }
  const int base = red[0];
  const int m = gcur[b];
  const int* a = aux + (size_t)b * BCAP;
  __syncthreads();
  for (int k = t; k < m; k += 256) atomicAdd(&c[a[k] >> 17], 1);
  __syncthreads();
  int val = (t < 128) ? c[t] : 0;
  red[t] = val;
  __syncthreads();
  for (int off = 1; off < 128; off <<= 1) {
    int add = (t >= off && t < 128) ? red[t - off] : 0;
    __syncthreads();
    if (t < 128) red[t] += add;
    __syncthreads();
  }
  if (t < 128) {
    int excl = red[t] - val + base;
    int node = b * 128 + t;
    if (node < NN) {
      row_ptr[node] = excl;
      dinv[node] = rsqrtf((float)(val + 1));
      cur[t] = excl;
    }
  }
  if (b == NBKT - 1 && t == 0) row_ptr[NN] = base + m;
  __syncthreads();
  for (int k = t; k < m; k += 256) {
    int pk2 = a[k];
    int pos = atomicAdd(&cur[pk2 >> 17], 1);
    col[pos] = pk2 & 0x1FFFF;
  }
}

// ---------------- MFMA GEMM (padding rows written as zeros) ----------------
template <int COUT, bool AFP32>
__global__ __launch_bounds__(256) void k_gemm_mfma(const void* __restrict__ Av,
                                                   const uint* __restrict__ Wt,
                                                   const float* __restrict__ dinv,
                                                   unsigned short* __restrict__ T) {
  constexpr int NT = COUT / 16;
  __shared__ __align__(16) uint Wlds[4 * NT * 64 * 4];
  __shared__ __align__(16) unsigned short Obuf[64 * COUT];
  const int t = threadIdx.x;
  {
    const uint4* src = (const uint4*)Wt;
    uint4* dst = (uint4*)Wlds;
    for (int i = t; i < 4 * NT * 64; i += 256) dst[i] = src[i];
  }
  __syncthreads();

  const int wv = t >> 6, lane = t & 63;
  const int n = lane & 15, quad = lane >> 4;
  const int rbase = blockIdx.x * 64 + wv * 16;

  union AB { uint4 u; s16x8 s; };
  AB a[4];
  if constexpr (AFP32) {
    const float* A = (const float*)Av;
    int row = rbase + n;
    if (row >= NN) row = NN - 1;
    const float* ap = A + (size_t)row * 128;
#pragma unroll
    for (int ks = 0; ks < 4; ++ks) {
      float4 v0 = *(const float4*)(ap + ks * 32 + quad * 8);
      float4 v1 = *(const float4*)(ap + ks * 32 + quad * 8 + 4);
      a[ks].u.x = (uint)f2bf(v0.x) | ((uint)f2bf(v0.y) << 16);
      a[ks].u.y = (uint)f2bf(v0.z) | ((uint)f2bf(v0.w) << 16);
      a[ks].u.z = (uint)f2bf(v1.x) | ((uint)f2bf(v1.y) << 16);
      a[ks].u.w = (uint)f2bf(v1.z) | ((uint)f2bf(v1.w) << 16);
    }
  } else {
    const uint4* A = (const uint4*)Av;
    int row = rbase + n;
#pragma unroll
    for (int ks = 0; ks < 4; ++ks) a[ks].u = A[(size_t)row * 16 + ks * 4 + quad];
  }

  f32x4 acc[NT];
#pragma unroll
  for (int tl = 0; tl < NT; ++tl) acc[tl] = (f32x4){0.f, 0.f, 0.f, 0.f};

#pragma unroll
  for (int ks = 0; ks < 4; ++ks) {
#pragma unroll
    for (int tl = 0; tl < NT; ++tl) {
      AB b;
      b.u = *(const uint4*)&Wlds[((ks * NT + tl) * 64 + lane) * 4];
      acc[tl] = __builtin_amdgcn_mfma_f32_16x16x32_bf16(a[ks].s, b.s, acc[tl], 0, 0, 0);
    }
  }

  float4 dv = *(const float4*)(dinv + rbase + quad * 4);
  float dvv[4] = {dv.x, dv.y, dv.z, dv.w};
  unsigned short* ob = Obuf + wv * 16 * COUT;
#pragma unroll
  for (int tl = 0; tl < NT; ++tl)
#pragma unroll
    for (int r = 0; r < 4; ++r)
      ob[(quad * 4 + r) * COUT + tl * 16 + n] = f2bf(acc[tl][r] * dvv[r]);

  uint4* gdst = (uint4*)(T + (size_t)rbase * COUT);
  constexpr int ITER = COUT / 32;
#pragma unroll
  for (int i = 0; i < ITER; ++i) {
    int off16 = i * 64 + lane;
    int lrow = (off16 * 8) / COUT;
    uint4 v = make_uint4(0u, 0u, 0u, 0u);
    if (rbase + lrow < NN) v = *(const uint4*)&ob[off16 * 8];
    gdst[off16] = v;
  }
}

// ---------------- gather layers 1/2: declamped main loop ----------------
// An[i] = bf16(relu(dinv[i]*(T[i]+sum T[col])+b)). 4 edge-groups x 16 lanes
// x uint4, 4-deep unroll; full iterations need no clamping, one clamped tail.
__global__ __launch_bounds__(256) void k_gather12(const int* __restrict__ row_ptr,
                                                  const int* __restrict__ col,
                                                  const uint4* __restrict__ T4,
                                                  const float* __restrict__ dinv,
                                                  const float* __restrict__ bias,
                                                  uint4* __restrict__ An) {
  int w = (blockIdx.x * 256 + threadIdx.x) >> 6;
  int lane = threadIdx.x & 63;
  if (w >= NN) return;
  int s = row_ptr[w], tend = row_ptr[w + 1];
  const int q = lane >> 4;   // edge group 0..3
  const int cl = lane & 15;  // uint4 (8 channels) within 256B row
  float acc[8] = {0.f, 0.f, 0.f, 0.f, 0.f, 0.f, 0.f, 0.f};
  if (q == 0) {  // self-loop term
    uint4 u = T4[(size_t)w * 16 + cl];
    upadd(u.x, acc[0], acc[1]);
    upadd(u.y, acc[2], acc[3]);
    upadd(u.z, acc[4], acc[5]);
    upadd(u.w, acc[6], acc[7]);
  }
  const int d = tend - s;
  const int nfull = d >> 4;
  int e = s + q;
  for (int it = 0; it < nfull; ++it, e += 16) {  // no clamping
    int c0 = col[e], c1 = col[e + 4], c2 = col[e + 8], c3 = col[e + 12];
    uint4 v0 = T4[(size_t)c0 * 16 + cl];
    uint4 v1 = T4[(size_t)c1 * 16 + cl];
    uint4 v2 = T4[(size_t)c2 * 16 + cl];
    uint4 v3 = T4[(size_t)c3 * 16 + cl];
    upadd(v0.x, acc[0], acc[1]); upadd(v0.y, acc[2], acc[3]);
    upadd(v0.z, acc[4], acc[5]); upadd(v0.w, acc[6], acc[7]);
    upadd(v1.x, acc[0], acc[1]); upadd(v1.y, acc[2], acc[3]);
    upadd(v1.z, acc[4], acc[5]); upadd(v1.w, acc[6], acc[7]);
    upadd(v2.x, acc[0], acc[1]); upadd(v2.y, acc[2], acc[3]);
    upadd(v2.z, acc[4], acc[5]); upadd(v2.w, acc[6], acc[7]);
    upadd(v3.x, acc[0], acc[1]); upadd(v3.y, acc[2], acc[3]);
    upadd(v3.z, acc[4], acc[5]); upadd(v3.w, acc[6], acc[7]);
  }
  if (d & 15) {  // clamped remainder (row NN is all-zero)
    const int m = tend - 1;
    int i0 = e, i1 = e + 4, i2 = e + 8, i3 = e + 12;
    int c0 = col[min(i0, m)], c1 = col[min(i1, m)];
    int c2 = col[min(i2, m)], c3 = col[min(i3, m)];
    c0 = (i0 < tend) ? c0 : NN;
    c1 = (i1 < tend) ? c1 : NN;
    c2 = (i2 < tend) ? c2 : NN;
    c3 = (i3 < tend) ? c3 : NN;
    uint4 v0 = T4[(size_t)c0 * 16 + cl];
    uint4 v1 = T4[(size_t)c1 * 16 + cl];
    uint4 v2 = T4[(size_t)c2 * 16 + cl];
    uint4 v3 = T4[(size_t)c3 * 16 + cl];
    upadd(v0.x, acc[0], acc[1]); upadd(v0.y, acc[2], acc[3]);
    upadd(v0.z, acc[4], acc[5]); upadd(v0.w, acc[6], acc[7]);
    upadd(v1.x, acc[0], acc[1]); upadd(v1.y, acc[2], acc[3]);
    upadd(v1.z, acc[4], acc[5]); upadd(v1.w, acc[6], acc[7]);
    upadd(v2.x, acc[0], acc[1]); upadd(v2.y, acc[2], acc[3]);
    upadd(v2.z, acc[4], acc[5]); upadd(v2.w, acc[6], acc[7]);
    upadd(v3.x, acc[0], acc[1]); upadd(v3.y, acc[2], acc[3]);
    upadd(v3.z, acc[4], acc[5]); upadd(v3.w, acc[6], acc[7]);
  }
#pragma unroll
  for (int i = 0; i < 8; ++i) {
    acc[i] += __shfl_down(acc[i], 16, 64);
    acc[i] += __shfl_down(acc[i], 32, 64);
  }
  if (q == 0) {
    float4 b0 = *(const float4*)&bias[cl * 8];
    float4 b1 = *(const float4*)&bias[cl * 8 + 4];
    float dv = dinv[w];
    float r[8];
    r[0] = fmaxf(fmaf(dv, acc[0], b0.x), 0.f);
    r[1] = fmaxf(fmaf(dv, acc[1], b0.y), 0.f);
    r[2] = fmaxf(fmaf(dv, acc[2], b0.z), 0.f);
    r[3] = fmaxf(fmaf(dv, acc[3], b0.w), 0.f);
    r[4] = fmaxf(fmaf(dv, acc[4], b1.x), 0.f);
    r[5] = fmaxf(fmaf(dv, acc[5], b1.y), 0.f);
    r[6] = fmaxf(fmaf(dv, acc[6], b1.z), 0.f);
    r[7] = fmaxf(fmaf(dv, acc[7], b1.w), 0.f);
    uint4 o;
    o.x = (uint)f2bf(r[0]) | ((uint)f2bf(r[1]) << 16);
    o.y = (uint)f2bf(r[2]) | ((uint)f2bf(r[3]) << 16);
    o.z = (uint)f2bf(r[4]) | ((uint)f2bf(r[5]) << 16);
    o.w = (uint)f2bf(r[6]) | ((uint)f2bf(r[7]) << 16);
    An[(size_t)w * 16 + cl] = o;
  }
}

// ---------------- gather layer 3: declamped, bf16 out ----------------
__global__ __launch_bounds__(256) void k_gather3(const int* __restrict__ row_ptr,
                                                 const int* __restrict__ col,
                                                 const uint4* __restrict__ T4,
                                                 uint4* __restrict__ G3) {
  int w = (blockIdx.x * 256 + threadIdx.x) >> 6;
  int lane = threadIdx.x & 63;
  if (w >= NN) return;
  int s = row_ptr[w], tend = row_ptr[w + 1];
  const int g = lane >> 3;  // edge group 0..7
  const int cl = lane & 7;  // uint4 (8 channels) within 128B row
  float acc[8] = {0.f, 0.f, 0.f, 0.f, 0.f, 0.f, 0.f, 0.f};
  if (g == 0) {
    uint4 u = T4[(size_t)w * 8 + cl];
    upadd(u.x, acc[0], acc[1]);
    upadd(u.y, acc[2], acc[3]);
    upadd(u.z, acc[4], acc[5]);
    upadd(u.w, acc[6], acc[7]);
  }
  const int d = tend - s;
  const int nfull = d >> 4;
  int e = s + g;
  for (int it = 0; it < nfull; ++it, e += 16) {
    int c0 = col[e], c1 = col[e + 8];
    uint4 v0 = T4[(size_t)c0 * 8 + cl];
    uint4 v1 = T4[(size_t)c1 * 8 + cl];
    upadd(v0.x, acc[0], acc[1]); upadd(v0.y, acc[2], acc[3]);
    upadd(v0.z, acc[4], acc[5]); upadd(v0.w, acc[6], acc[7]);
    upadd(v1.x, acc[0], acc[1]); upadd(v1.y, acc[2], acc[3]);
    upadd(v1.z, acc[4], acc[5]); upadd(v1.w, acc[6], acc[7]);
  }
  if (d & 15) {
    const int m = tend - 1;
    int i0 = e, i1 = e + 8;
    int c0 = col[min(i0, m)], c1 = col[min(i1, m)];
    c0 = (i0 < tend) ? c0 : NN;
    c1 = (i1 < tend) ? c1 : NN;
    uint4 v0 = T4[(size_t)c0 * 8 + cl];
    uint4 v1 = T4[(size_t)c1 * 8 + cl];
    upadd(v0.x, acc[0], acc[1]); upadd(v0.y, acc[2], acc[3]);
    upadd(v0.z, acc[4], acc[5]); upadd(v0.w, acc[6], acc[7]);
    upadd(v1.x, acc[0], acc[1]); upadd(v1.y, acc[2], acc[3]);
    upadd(v1.z, acc[4], acc[5]); upadd(v1.w, acc[6], acc[7]);
  }
#pragma unroll
  for (int i = 0; i < 8; ++i) {
    acc[i] += __shfl_down(acc[i], 8, 64);
    acc[i] += __shfl_down(acc[i], 16, 64);
    acc[i] += __shfl_down(acc[i], 32, 64);
  }
  if (g == 0) {
    uint4 o;
    o.x = (uint)f2bf(acc[0]) | ((uint)f2bf(acc[1]) << 16);
    o.y = (uint)f2bf(acc[2]) | ((uint)f2bf(acc[3]) << 16);
    o.z = (uint)f2bf(acc[4]) | ((uint)f2bf(acc[5]) << 16);
    o.w = (uint)f2bf(acc[6]) | ((uint)f2bf(acc[7]) << 16);
    G3[(size_t)w * 8 + cl] = o;  // bf16 row, 128B
  }
}

// ---------------- pair decode: bf16 G3, 4 pairs/wave ----------------
__global__ __launch_bounds__(256) void k_decode(const int* __restrict__ ni,
                                                const int* __restrict__ nj,
                                                const uint2* __restrict__ G3,
                                                const float* __restrict__ dinv,
                                                const float* __restrict__ b3,
                                                float* __restrict__ out) {
  int p = blockIdx.x * 16 + (threadIdx.x >> 4);
  int cl = threadIdx.x & 15;
  int i = ni[p], j = nj[p];
  uint2 ui = G3[(size_t)i * 16 + cl];
  uint2 uj = G3[(size_t)j * 16 + cl];
  float4 bb = *(const float4*)&b3[cl * 4];
  float di = dinv[i], dj = dinv[j];
  float gi0 = __uint_as_float(ui.x << 16), gi1 = __uint_as_float(ui.x & 0xffff0000u);
  float gi2 = __uint_as_float(ui.y << 16), gi3 = __uint_as_float(ui.y & 0xffff0000u);
  float gj0 = __uint_as_float(uj.x << 16), gj1 = __uint_as_float(uj.x & 0xffff0000u);
  float gj2 = __uint_as_float(uj.y << 16), gj3 = __uint_as_float(uj.y & 0xffff0000u);
  float v = fmaf(di, gi0, bb.x) * fmaf(dj, gj0, bb.x) +
            fmaf(di, gi1, bb.y) * fmaf(dj, gj1, bb.y) +
            fmaf(di, gi2, bb.z) * fmaf(dj, gj2, bb.z) +
            fmaf(di, gi3, bb.w) * fmaf(dj, gj3, bb.w);
  v += __shfl_xor(v, 1, 64);
  v += __shfl_xor(v, 2, 64);
  v += __shfl_xor(v, 4, 64);
  v += __shfl_xor(v, 8, 64);
  if (cl == 0) out[p] = v;
}

extern "C" void kernel_launch(void* const* d_in, const int* in_sizes, int n_in,
                              void* d_out, int out_size, void* d_ws, size_t ws_size,
                              hipStream_t stream) {
  const float* x  = (const float*)d_in[0];
  const int*   ei = (const int*)d_in[1];
  const int*   ni = (const int*)d_in[2];
  const int*   nj = (const int*)d_in[3];
  const float* W1 = (const float*)d_in[4];
  const float* b1 = (const float*)d_in[5];
  const float* W2 = (const float*)d_in[6];
  const float* b2 = (const float*)d_in[7];
  const float* W3 = (const float*)d_in[8];
  const float* b3 = (const float*)d_in[9];
  float* out = (float*)d_out;

  // ws carve (4-byte words)
  float* dinv    = (float*)d_ws;              // 102400
  int*   row_ptr = (int*)(dinv + 102400);     // 102400 (NN+1 used)
  int*   gcur    = row_ptr + 102400;          // 1024 (relative counts)
  int*   col     = gcur + 1024;               // NE
  uint*  Wt1     = (uint*)(col + NE);         // 8192
  uint*  Wt2     = Wt1 + 8192;                // 8192
  uint*  Wt3     = Wt2 + 8192;                // 4096
  uint*  Tbf     = Wt3 + 4096;                // NNP*64 (bf16 [NNP][128])
  uint*  Abf     = Tbf + (size_t)NNP * 64;    // NNP*64
  uint*  G3      = Abf + (size_t)NNP * 64;    // NNP*32 (bf16 [NNP][64])
  int*   aux     = (int*)G3;  // 12.6 MB arena, dead before gather3 writes G3

  // ---- setup (gcur + weight pre-pack) + CSR build ----
  k_setup<<<24, 256, 0, stream>>>(W1, W2, W3, Wt1, Wt2, Wt3, gcur);
  k_bucket<<<(NE + BKB - 1) / BKB, 256, 0, stream>>>(ei, gcur, aux);
  k_csr<<<NBKT, 256, 0, stream>>>(gcur, aux, row_ptr, dinv, col);

  const int GB = NNP / 64;                 // 1563
  const int GATB = (NN * 64 + 255) / 256;  // 25000

  // layer 1 (x fp32 -> Tbf bf16)
  k_gemm_mfma<128, true><<<GB, 256, 0, stream>>>(x, Wt1, dinv, (unsigned short*)Tbf);
  k_gather12<<<GATB, 256, 0, stream>>>(row_ptr, col, (const uint4*)Tbf, dinv, b1, (uint4*)Abf);
  // layer 2
  k_gemm_mfma<128, false><<<GB, 256, 0, stream>>>(Abf, Wt2, dinv, (unsigned short*)Tbf);
  k_gather12<<<GATB, 256, 0, stream>>>(row_ptr, col, (const uint4*)Tbf, dinv, b2, (uint4*)Abf);
  // layer 3 (COUT=64)
  k_gemm_mfma<64, false><<<GB, 256, 0, stream>>>(Abf, Wt3, dinv, (unsigned short*)Tbf);
  k_gather3<<<GATB, 256, 0, stream>>>(row_ptr, col, (const uint4*)Tbf, (uint4*)G3);
  // decode (bf16 G3)
  k_decode<<<NP / 16, 256, 0, stream>>>(ni, nj, (const uint2*)G3, dinv, b3, out);
}

// Round 12
// 330.159 us; speedup vs baseline: 2.1073x; 1.0285x over previous
//
#include <hip/hip_runtime.h>

#define NN 100000
#define NNP 100032   // padded rows; rows NN..NNP-1 of T buffers are zero
#define NE 1600000
#define NP 200000
#define NBKT 782
#define BCAP 3072
#define BKB 4096

typedef short s16x8 __attribute__((ext_vector_type(8)));
typedef float f32x4 __attribute__((ext_vector_type(4)));

__device__ __forceinline__ unsigned short f2bf(float f) {  // RNE fp32->bf16
  unsigned int u = __float_as_uint(f);
  u += 0x7fffu + ((u >> 16) & 1u);
  return (unsigned short)(u >> 16);
}

__device__ __forceinline__ void upadd(uint u, float& lo, float& hi) {
  lo += __uint_as_float(u << 16);
  hi += __uint_as_float(u & 0xffff0000u);
}

// ---------------- setup: gcur zero + W pre-pack ----------------
template <int NT>
__device__ __forceinline__ void prepw_dev(const float* __restrict__ W,
                                          uint* __restrict__ Wt, int tid) {
  constexpr int COUT = NT * 16;
  if (tid >= 4 * NT * 64) return;
  int lane = tid & 63, comb = tid >> 6;
  int ks = comb / NT, tl = comb % NT;
  int q = lane >> 4, n = lane & 15;
  uint w[4];
#pragma unroll
  for (int jj = 0; jj < 4; ++jj) {
    int k0 = ks * 32 + q * 8 + 2 * jj;
    uint lo = f2bf(W[k0 * COUT + tl * 16 + n]);
    uint hi = f2bf(W[(k0 + 1) * COUT + tl * 16 + n]);
    w[jj] = lo | (hi << 16);
  }
  ((uint4*)Wt)[comb * 64 + lane] = make_uint4(w[0], w[1], w[2], w[3]);
}

__global__ __launch_bounds__(256) void k_setup(const float* __restrict__ W1,
                                               const float* __restrict__ W2,
                                               const float* __restrict__ W3,
                                               uint* __restrict__ Wt1,
                                               uint* __restrict__ Wt2,
                                               uint* __restrict__ Wt3,
                                               int* __restrict__ gcur) {
  int b = blockIdx.x, t = threadIdx.x;
  if (b < 4) {
    int i = b * 256 + t;
    if (i < 1024) gcur[i] = 0;
  } else if (b < 12) {
    prepw_dev<8>(W1, Wt1, (b - 4) * 256 + t);
  } else if (b < 20) {
    prepw_dev<8>(W2, Wt2, (b - 12) * 256 + t);
  } else {
    prepw_dev<4>(W3, Wt3, (b - 20) * 256 + t);
  }
}

// ---------------- bucket-sort phase A ----------------
__global__ __launch_bounds__(256) void k_bucket(const int* __restrict__ ei,
                                                int* __restrict__ gcur,
                                                int* __restrict__ aux) {
  __shared__ int cnt[1024];
  __shared__ int scn[1024];
  __shared__ int cur[1024];
  __shared__ int sc[256];
  __shared__ int sorted[BKB];
  __shared__ unsigned short sbkt[BKB];
  const int t = threadIdx.x;
  const int base = blockIdx.x * BKB;

  for (int i = t; i < 1024; i += 256) cnt[i] = 0;
  __syncthreads();

  int pk[16], bk[16];
#pragma unroll
  for (int i = 0; i < 16; ++i) {
    int e = base + t + 256 * i;
    if (e < NE) {
      int src = ei[e], dst = ei[NE + e];
      bk[i] = dst >> 7;
      pk[i] = src | ((dst & 127) << 17);
      atomicAdd(&cnt[bk[i]], 1);
    } else {
      bk[i] = -1;
    }
  }
  __syncthreads();

  int s0 = cnt[4 * t], s1 = cnt[4 * t + 1], s2 = cnt[4 * t + 2], s3 = cnt[4 * t + 3];
  int local = s0 + s1 + s2 + s3;
  sc[t] = local;
  __syncthreads();
  for (int off = 1; off < 256; off <<= 1) {
    int a = (t >= off) ? sc[t - off] : 0;
    __syncthreads();
    sc[t] += a;
    __syncthreads();
  }
  int b0 = sc[t] - local;
  scn[4 * t] = b0;
  scn[4 * t + 1] = b0 + s0;
  scn[4 * t + 2] = b0 + s0 + s1;
  scn[4 * t + 3] = b0 + s0 + s1 + s2;
  cur[4 * t] = scn[4 * t];
  cur[4 * t + 1] = scn[4 * t + 1];
  cur[4 * t + 2] = scn[4 * t + 2];
  cur[4 * t + 3] = scn[4 * t + 3];
  __syncthreads();
  const int tot = sc[255];

#pragma unroll
  for (int i = 0; i < 16; ++i) {
    if (bk[i] >= 0) {
      int pos = atomicAdd(&cur[bk[i]], 1);
      sorted[pos] = pk[i];
      sbkt[pos] = (unsigned short)bk[i];
    }
  }
  __syncthreads();

  // gcur holds RELATIVE counts; arena base is b*BCAP
  for (int b = t; b < 1024; b += 256) {
    int c = cnt[b];
    if (c > 0) cur[b] = b * BCAP + atomicAdd(&gcur[b], c);
  }
  __syncthreads();

  for (int k = t; k < tot; k += 256) {
    int b = sbkt[k];
    aux[cur[b] + (k - scn[b])] = sorted[k];
  }
}

// ---------------- merged CSR finalize ----------------
__global__ __launch_bounds__(256) void k_csr(const int* __restrict__ gcur,
                                             const int* __restrict__ aux,
                                             int* __restrict__ row_ptr,
                                             float* __restrict__ dinv,
                                             int* __restrict__ col) {
  __shared__ int red[256];
  __shared__ int c[128];
  __shared__ int cur[128];
  const int b = blockIdx.x, t = threadIdx.x;
  int p = 0;
  for (int i = t; i < b; i += 256) p += gcur[i];
  red[t] = p;
  if (t < 128) c[t] = 0;
  __syncthreads();
  for (int off = 128; off > 0; off >>= 1) {
    if (t < off) red[t] += red[t + off];
    __syncthreads();
  }
  const int base = red[0];
  const int m = gcur[b];
  const int* a = aux + (size_t)b * BCAP;
  __syncthreads();
  for (int k = t; k < m; k += 256) atomicAdd(&c[a[k] >> 17], 1);
  __syncthreads();
  int val = (t < 128) ? c[t] : 0;
  red[t] = val;
  __syncthreads();
  for (int off = 1; off < 128; off <<= 1) {
    int add = (t >= off && t < 128) ? red[t - off] : 0;
    __syncthreads();
    if (t < 128) red[t] += add;
    __syncthreads();
  }
  if (t < 128) {
    int excl = red[t] - val + base;
    int node = b * 128 + t;
    if (node < NN) {
      row_ptr[node] = excl;
      dinv[node] = rsqrtf((float)(val + 1));
      cur[t] = excl;
    }
  }
  if (b == NBKT - 1 && t == 0) row_ptr[NN] = base + m;
  __syncthreads();
  for (int k = t; k < m; k += 256) {
    int pk2 = a[k];
    int pos = atomicAdd(&cur[pk2 >> 17], 1);
    col[pos] = pk2 & 0x1FFFF;
  }
}

// ---------------- MFMA GEMM layer 1 (x fp32 -> T1 bf16) ----------------
__global__ __launch_bounds__(256) void k_gemm1(const float* __restrict__ A,
                                               const uint* __restrict__ Wt,
                                               const float* __restrict__ dinv,
                                               unsigned short* __restrict__ T) {
  constexpr int NT = 8, COUT = 128;
  __shared__ __align__(16) uint Wlds[4 * NT * 64 * 4];
  __shared__ __align__(16) unsigned short Obuf[64 * COUT];
  const int t = threadIdx.x;
  {
    const uint4* src = (const uint4*)Wt;
    uint4* dst = (uint4*)Wlds;
    for (int i = t; i < 4 * NT * 64; i += 256) dst[i] = src[i];
  }
  __syncthreads();

  const int wv = t >> 6, lane = t & 63;
  const int n = lane & 15, quad = lane >> 4;
  const int rbase = blockIdx.x * 64 + wv * 16;

  union AB { uint4 u; s16x8 s; };
  AB a[4];
  {
    int row = rbase + n;
    if (row >= NN) row = NN - 1;
    const float* ap = A + (size_t)row * 128;
#pragma unroll
    for (int ks = 0; ks < 4; ++ks) {
      float4 v0 = *(const float4*)(ap + ks * 32 + quad * 8);
      float4 v1 = *(const float4*)(ap + ks * 32 + quad * 8 + 4);
      a[ks].u.x = (uint)f2bf(v0.x) | ((uint)f2bf(v0.y) << 16);
      a[ks].u.y = (uint)f2bf(v0.z) | ((uint)f2bf(v0.w) << 16);
      a[ks].u.z = (uint)f2bf(v1.x) | ((uint)f2bf(v1.y) << 16);
      a[ks].u.w = (uint)f2bf(v1.z) | ((uint)f2bf(v1.w) << 16);
    }
  }

  f32x4 acc[NT];
#pragma unroll
  for (int tl = 0; tl < NT; ++tl) acc[tl] = (f32x4){0.f, 0.f, 0.f, 0.f};

#pragma unroll
  for (int ks = 0; ks < 4; ++ks) {
#pragma unroll
    for (int tl = 0; tl < NT; ++tl) {
      AB b;
      b.u = *(const uint4*)&Wlds[((ks * NT + tl) * 64 + lane) * 4];
      acc[tl] = __builtin_amdgcn_mfma_f32_16x16x32_bf16(a[ks].s, b.s, acc[tl], 0, 0, 0);
    }
  }

  float4 dv = *(const float4*)(dinv + rbase + quad * 4);
  float dvv[4] = {dv.x, dv.y, dv.z, dv.w};
  unsigned short* ob = Obuf + wv * 16 * COUT;
#pragma unroll
  for (int tl = 0; tl < NT; ++tl)
#pragma unroll
    for (int r = 0; r < 4; ++r)
      ob[(quad * 4 + r) * COUT + tl * 16 + n] = f2bf(acc[tl][r] * dvv[r]);

  uint4* gdst = (uint4*)(T + (size_t)rbase * COUT);
#pragma unroll
  for (int i = 0; i < 4; ++i) {
    int off16 = i * 64 + lane;
    int lrow = (off16 * 8) / COUT;
    uint4 v = make_uint4(0u, 0u, 0u, 0u);
    if (rbase + lrow < NN) v = *(const uint4*)&ob[off16 * 8];
    gdst[off16] = v;
  }
}

// ---------------- fused gather + GEMM, LOW-LDS (layers 2, 3) ----------------
// Block = 16 nodes, 4 waves; each wave gathers 4 node-rows of h (R11-style
// declamped loop) into a 4.4 KB padded LDS buffer. Then all 4 waves MFMA the
// 16x128 A-tile against W **streamed from global (L1-hot)** — no W-LDS, so
// occupancy stays ~8 blocks/CU (R10's 30%-occupancy failure mode avoided).
// Output staged through the SAME LDS buffer (barrier-separated) for coalesced
// bf16 stores; pad rows (>= NN) written as zeros.
template <int COUT>
__global__ __launch_bounds__(256) void k_gg(const int* __restrict__ row_ptr,
                                            const int* __restrict__ col,
                                            const uint4* __restrict__ T4,
                                            const float* __restrict__ dinv,
                                            const float* __restrict__ bias,
                                            const uint4* __restrict__ Wt,
                                            unsigned short* __restrict__ Tout) {
  constexpr int NT = COUT / 16;   // 8 or 4
  constexpr int TLW = NT / 4;     // col-tiles per wave: 2 or 1
  constexpr int OSTR = COUT + 8;  // Obuf row stride (ushorts), 16B-aligned rows
  __shared__ __align__(16) uint4 Alds[16 * 17];  // 4352 B; reused as Obuf
  const int t = threadIdx.x, wv = t >> 6, lane = t & 63;
  const int nbase = blockIdx.x * 16;
  const int q = lane >> 4, cl = lane & 15;

  // ---- phase 1: gather 4 nodes per wave ----
#pragma unroll 1
  for (int i = 0; i < 4; ++i) {
    const int node = nbase + wv * 4 + i;
    int s = 0, tend = 0;
    if (node < NN) { s = row_ptr[node]; tend = row_ptr[node + 1]; }
    float acc[8] = {0.f, 0.f, 0.f, 0.f, 0.f, 0.f, 0.f, 0.f};
    if (q == 0) {  // self-loop (node < NNP always valid; pad rows are zero)
      uint4 u = T4[(size_t)node * 16 + cl];
      upadd(u.x, acc[0], acc[1]);
      upadd(u.y, acc[2], acc[3]);
      upadd(u.z, acc[4], acc[5]);
      upadd(u.w, acc[6], acc[7]);
    }
    const int d = tend - s;
    const int nfull = d >> 4;
    int e = s + q;
    for (int it = 0; it < nfull; ++it, e += 16) {  // declamped main loop
      int c0 = col[e], c1 = col[e + 4], c2 = col[e + 8], c3 = col[e + 12];
      uint4 v0 = T4[(size_t)c0 * 16 + cl];
      uint4 v1 = T4[(size_t)c1 * 16 + cl];
      uint4 v2 = T4[(size_t)c2 * 16 + cl];
      uint4 v3 = T4[(size_t)c3 * 16 + cl];
      upadd(v0.x, acc[0], acc[1]); upadd(v0.y, acc[2], acc[3]);
      upadd(v0.z, acc[4], acc[5]); upadd(v0.w, acc[6], acc[7]);
      upadd(v1.x, acc[0], acc[1]); upadd(v1.y, acc[2], acc[3]);
      upadd(v1.z, acc[4], acc[5]); upadd(v1.w, acc[6], acc[7]);
      upadd(v2.x, acc[0], acc[1]); upadd(v2.y, acc[2], acc[3]);
      upadd(v2.z, acc[4], acc[5]); upadd(v2.w, acc[6], acc[7]);
      upadd(v3.x, acc[0], acc[1]); upadd(v3.y, acc[2], acc[3]);
      upadd(v3.z, acc[4], acc[5]); upadd(v3.w, acc[6], acc[7]);
    }
    if (d & 15) {  // clamped remainder (row NN is all-zero)
      const int m = tend - 1;
      int i0 = e, i1 = e + 4, i2 = e + 8, i3 = e + 12;
      int c0 = col[min(i0, m)], c1 = col[min(i1, m)];
      int c2 = col[min(i2, m)], c3 = col[min(i3, m)];
      c0 = (i0 < tend) ? c0 : NN;
      c1 = (i1 < tend) ? c1 : NN;
      c2 = (i2 < tend) ? c2 : NN;
      c3 = (i3 < tend) ? c3 : NN;
      uint4 v0 = T4[(size_t)c0 * 16 + cl];
      uint4 v1 = T4[(size_t)c1 * 16 + cl];
      uint4 v2 = T4[(size_t)c2 * 16 + cl];
      uint4 v3 = T4[(size_t)c3 * 16 + cl];
      upadd(v0.x, acc[0], acc[1]); upadd(v0.y, acc[2], acc[3]);
      upadd(v0.z, acc[4], acc[5]); upadd(v0.w, acc[6], acc[7]);
      upadd(v1.x, acc[0], acc[1]); upadd(v1.y, acc[2], acc[3]);
      upadd(v1.z, acc[4], acc[5]); upadd(v1.w, acc[6], acc[7]);
      upadd(v2.x, acc[0], acc[1]); upadd(v2.y, acc[2], acc[3]);
      upadd(v2.z, acc[4], acc[5]); upadd(v2.w, acc[6], acc[7]);
      upadd(v3.x, acc[0], acc[1]); upadd(v3.y, acc[2], acc[3]);
      upadd(v3.z, acc[4], acc[5]); upadd(v3.w, acc[6], acc[7]);
    }
#pragma unroll
    for (int k = 0; k < 8; ++k) {
      acc[k] += __shfl_down(acc[k], 16, 64);
      acc[k] += __shfl_down(acc[k], 32, 64);
    }
    if (q == 0) {
      float4 b0 = *(const float4*)&bias[cl * 8];
      float4 b1 = *(const float4*)&bias[cl * 8 + 4];
      float dv = dinv[node];  // pad nodes: finite garbage; rows zeroed at write
      float r[8];
      r[0] = fmaxf(fmaf(dv, acc[0], b0.x), 0.f);
      r[1] = fmaxf(fmaf(dv, acc[1], b0.y), 0.f);
      r[2] = fmaxf(fmaf(dv, acc[2], b0.z), 0.f);
      r[3] = fmaxf(fmaf(dv, acc[3], b0.w), 0.f);
      r[4] = fmaxf(fmaf(dv, acc[4], b1.x), 0.f);
      r[5] = fmaxf(fmaf(dv, acc[5], b1.y), 0.f);
      r[6] = fmaxf(fmaf(dv, acc[6], b1.z), 0.f);
      r[7] = fmaxf(fmaf(dv, acc[7], b1.w), 0.f);
      uint4 o;
      o.x = (uint)f2bf(r[0]) | ((uint)f2bf(r[1]) << 16);
      o.y = (uint)f2bf(r[2]) | ((uint)f2bf(r[3]) << 16);
      o.z = (uint)f2bf(r[4]) | ((uint)f2bf(r[5]) << 16);
      o.w = (uint)f2bf(r[6]) | ((uint)f2bf(r[7]) << 16);
      Alds[(wv * 4 + i) * 17 + cl] = o;
    }
  }
  __syncthreads();

  // ---- phase 2: 16x128 @ 128xCOUT, B-frags streamed from global (L1) ----
  const int n = lane & 15, quad = lane >> 4;
  union AB { uint4 u; s16x8 s; };
  AB a[4];
#pragma unroll
  for (int ks = 0; ks < 4; ++ks) a[ks].u = Alds[n * 17 + ks * 4 + quad];
  f32x4 acc2[TLW];
#pragma unroll
  for (int j = 0; j < TLW; ++j) acc2[j] = (f32x4){0.f, 0.f, 0.f, 0.f};
#pragma unroll
  for (int ks = 0; ks < 4; ++ks) {
#pragma unroll
    for (int j = 0; j < TLW; ++j) {
      int tl = wv * TLW + j;
      AB b;
      b.u = Wt[(ks * NT + tl) * 64 + lane];
      acc2[j] = __builtin_amdgcn_mfma_f32_16x16x32_bf16(a[ks].s, b.s, acc2[j], 0, 0, 0);
    }
  }
  __syncthreads();  // all waves done reading Alds -> safe to reuse as Obuf

  unsigned short* Obuf = (unsigned short*)Alds;
  float4 dv4 = *(const float4*)(dinv + nbase + quad * 4);
  float dvv[4] = {dv4.x, dv4.y, dv4.z, dv4.w};
#pragma unroll
  for (int j = 0; j < TLW; ++j) {
    int tl = wv * TLW + j;
#pragma unroll
    for (int r = 0; r < 4; ++r)
      Obuf[(quad * 4 + r) * OSTR + tl * 16 + n] = f2bf(acc2[j][r] * dvv[r]);
  }
  __syncthreads();

  if constexpr (COUT == 128) {
    int row = t >> 4, c16 = t & 15;
    uint4 v = make_uint4(0u, 0u, 0u, 0u);
    if (nbase + row < NN) v = *(const uint4*)&Obuf[row * OSTR + c16 * 8];
    ((uint4*)(Tout + (size_t)nbase * COUT))[row * 16 + c16] = v;
  } else {
    if (t < 128) {
      int row = t >> 3, c16 = t & 7;
      uint4 v = make_uint4(0u, 0u, 0u, 0u);
      if (nbase + row < NN) v = *(const uint4*)&Obuf[row * OSTR + c16 * 8];
      ((uint4*)(Tout + (size_t)nbase * COUT))[row * 8 + c16] = v;
    }
  }
}

// ---------------- gather layer 3: declamped, bf16 out ----------------
__global__ __launch_bounds__(256) void k_gather3(const int* __restrict__ row_ptr,
                                                 const int* __restrict__ col,
                                                 const uint4* __restrict__ T4,
                                                 uint4* __restrict__ G3) {
  int w = (blockIdx.x * 256 + threadIdx.x) >> 6;
  int lane = threadIdx.x & 63;
  if (w >= NN) return;
  int s = row_ptr[w], tend = row_ptr[w + 1];
  const int g = lane >> 3;
  const int cl = lane & 7;
  float acc[8] = {0.f, 0.f, 0.f, 0.f, 0.f, 0.f, 0.f, 0.f};
  if (g == 0) {
    uint4 u = T4[(size_t)w * 8 + cl];
    upadd(u.x, acc[0], acc[1]);
    upadd(u.y, acc[2], acc[3]);
    upadd(u.z, acc[4], acc[5]);
    upadd(u.w, acc[6], acc[7]);
  }
  const int d = tend - s;
  const int nfull = d >> 4;
  int e = s + g;
  for (int it = 0; it < nfull; ++it, e += 16) {
    int c0 = col[e], c1 = col[e + 8];
    uint4 v0 = T4[(size_t)c0 * 8 + cl];
    uint4 v1 = T4[(size_t)c1 * 8 + cl];
    upadd(v0.x, acc[0], acc[1]); upadd(v0.y, acc[2], acc[3]);
    upadd(v0.z, acc[4], acc[5]); upadd(v0.w, acc[6], acc[7]);
    upadd(v1.x, acc[0], acc[1]); upadd(v1.y, acc[2], acc[3]);
    upadd(v1.z, acc[4], acc[5]); upadd(v1.w, acc[6], acc[7]);
  }
  if (d & 15) {
    const int m = tend - 1;
    int i0 = e, i1 = e + 8;
    int c0 = col[min(i0, m)], c1 = col[min(i1, m)];
    c0 = (i0 < tend) ? c0 : NN;
    c1 = (i1 < tend) ? c1 : NN;
    uint4 v0 = T4[(size_t)c0 * 8 + cl];
    uint4 v1 = T4[(size_t)c1 * 8 + cl];
    upadd(v0.x, acc[0], acc[1]); upadd(v0.y, acc[2], acc[3]);
    upadd(v0.z, acc[4], acc[5]); upadd(v0.w, acc[6], acc[7]);
    upadd(v1.x, acc[0], acc[1]); upadd(v1.y, acc[2], acc[3]);
    upadd(v1.z, acc[4], acc[5]); upadd(v1.w, acc[6], acc[7]);
  }
#pragma unroll
  for (int i = 0; i < 8; ++i) {
    acc[i] += __shfl_down(acc[i], 8, 64);
    acc[i] += __shfl_down(acc[i], 16, 64);
    acc[i] += __shfl_down(acc[i], 32, 64);
  }
  if (g == 0) {
    uint4 o;
    o.x = (uint)f2bf(acc[0]) | ((uint)f2bf(acc[1]) << 16);
    o.y = (uint)f2bf(acc[2]) | ((uint)f2bf(acc[3]) << 16);
    o.z = (uint)f2bf(acc[4]) | ((uint)f2bf(acc[5]) << 16);
    o.w = (uint)f2bf(acc[6]) | ((uint)f2bf(acc[7]) << 16);
    G3[(size_t)w * 8 + cl] = o;
  }
}

// ---------------- pair decode: bf16 G3, 4 pairs/wave ----------------
__global__ __launch_bounds__(256) void k_decode(const int* __restrict__ ni,
                                                const int* __restrict__ nj,
                                                const uint2* __restrict__ G3,
                                                const float* __restrict__ dinv,
                                                const float* __restrict__ b3,
                                                float* __restrict__ out) {
  int p = blockIdx.x * 16 + (threadIdx.x >> 4);
  int cl = threadIdx.x & 15;
  int i = ni[p], j = nj[p];
  uint2 ui = G3[(size_t)i * 16 + cl];
  uint2 uj = G3[(size_t)j * 16 + cl];
  float4 bb = *(const float4*)&b3[cl * 4];
  float di = dinv[i], dj = dinv[j];
  float gi0 = __uint_as_float(ui.x << 16), gi1 = __uint_as_float(ui.x & 0xffff0000u);
  float gi2 = __uint_as_float(ui.y << 16), gi3 = __uint_as_float(ui.y & 0xffff0000u);
  float gj0 = __uint_as_float(uj.x << 16), gj1 = __uint_as_float(uj.x & 0xffff0000u);
  float gj2 = __uint_as_float(uj.y << 16), gj3 = __uint_as_float(uj.y & 0xffff0000u);
  float v = fmaf(di, gi0, bb.x) * fmaf(dj, gj0, bb.x) +
            fmaf(di, gi1, bb.y) * fmaf(dj, gj1, bb.y) +
            fmaf(di, gi2, bb.z) * fmaf(dj, gj2, bb.z) +
            fmaf(di, gi3, bb.w) * fmaf(dj, gj3, bb.w);
  v += __shfl_xor(v, 1, 64);
  v += __shfl_xor(v, 2, 64);
  v += __shfl_xor(v, 4, 64);
  v += __shfl_xor(v, 8, 64);
  if (cl == 0) out[p] = v;
}

extern "C" void kernel_launch(void* const* d_in, const int* in_sizes, int n_in,
                              void* d_out, int out_size, void* d_ws, size_t ws_size,
                              hipStream_t stream) {
  const float* x  = (const float*)d_in[0];
  const int*   ei = (const int*)d_in[1];
  const int*   ni = (const int*)d_in[2];
  const int*   nj = (const int*)d_in[3];
  const float* W1 = (const float*)d_in[4];
  const float* b1 = (const float*)d_in[5];
  const float* W2 = (const float*)d_in[6];
  const float* b2 = (const float*)d_in[7];
  const float* W3 = (const float*)d_in[8];
  const float* b3 = (const float*)d_in[9];
  float* out = (float*)d_out;

  // ws carve (4-byte words)
  float* dinv    = (float*)d_ws;              // 102400
  int*   row_ptr = (int*)(dinv + 102400);     // 102400 (NN+1 used)
  int*   gcur    = row_ptr + 102400;          // 1024 (relative counts)
  int*   col     = gcur + 1024;               // NE
  uint*  Wt1     = (uint*)(col + NE);         // 8192
  uint*  Wt2     = Wt1 + 8192;                // 8192
  uint*  Wt3     = Wt2 + 8192;                // 4096
  uint*  Tbf     = Wt3 + 4096;                // NNP*64: T1, later T3
  uint*  T2      = Tbf + (size_t)NNP * 64;    // NNP*64
  uint*  G3      = T2 + (size_t)NNP * 64;     // NNP*32 (bf16 [NNP][64])
  int*   aux     = (int*)G3;  // 12.6 MB arena, dead before gather3 writes G3

  // ---- setup (gcur + weight pre-pack) + CSR build ----
  k_setup<<<24, 256, 0, stream>>>(W1, W2, W3, Wt1, Wt2, Wt3, gcur);
  k_bucket<<<(NE + BKB - 1) / BKB, 256, 0, stream>>>(ei, gcur, aux);
  k_csr<<<NBKT, 256, 0, stream>>>(gcur, aux, row_ptr, dinv, col);

  const int GB = NNP / 64;                 // 1563
  const int FB = NNP / 16;                 // 6252
  const int GATB = (NN * 64 + 255) / 256;  // 25000

  // layer 1 (x fp32 -> T1 bf16)
  k_gemm1<<<GB, 256, 0, stream>>>(x, Wt1, dinv, (unsigned short*)Tbf);
  // layer 2: fused gather(T1)+relu/bias(b1)+GEMM(W2)*dinv -> T2
  k_gg<128><<<FB, 256, 0, stream>>>(row_ptr, col, (const uint4*)Tbf, dinv, b1,
                                    (const uint4*)Wt2, (unsigned short*)T2);
  // layer 3: fused gather(T2)+relu/bias(b2)+GEMM(W3)*dinv -> T3 (reuses Tbf)
  k_gg<64><<<FB, 256, 0, stream>>>(row_ptr, col, (const uint4*)T2, dinv, b2,
                                   (const uint4*)Wt3, (unsigned short*)Tbf);
  // final aggregation (T3 -> G3 bf16)
  k_gather3<<<GATB, 256, 0, stream>>>(row_ptr, col, (const uint4*)Tbf, (uint4*)G3);
  // decode (bf16 G3)
  k_decode<<<NP / 16, 256, 0, stream>>>(ni, nj, (const uint2*)G3, dinv, b3, out);
}